// Round 9
// baseline (1497.388 us; speedup 1.0000x reference)
//
#include <hip/hip_runtime.h>
#include <cmath>

static constexpr int NN = 50000;   // nodes
static constexpr int EE = 500000;  // edges

typedef short v8s __attribute__((ext_vector_type(8)));
typedef float v4f __attribute__((ext_vector_type(4)));

__device__ inline short f2bf(float x){
  union{float f; unsigned u;} v{x};
  unsigned r = v.u + 0x7fffu + ((v.u >> 16) & 1u);
  return (short)(r >> 16);
}
__device__ inline float b2f(short s){
  union{unsigned u; float f;} v; v.u = ((unsigned)(unsigned short)s) << 16; return v.f;
}

// ---------------- graph prep ----------------

__global__ __launch_bounds__(256)
void count_deg_k(const int* __restrict__ dst, int* __restrict__ cnt, int e_total){
  int e = blockIdx.x*256 + threadIdx.x;
  if (e < e_total) atomicAdd(&cnt[dst[e]], 1);
}

__global__ __launch_bounds__(1024)
void scan_block_k(const int* __restrict__ cnt, int* __restrict__ pre,
                  int* __restrict__ bsum, int n){
  __shared__ int tmp[1024];
  int b = blockIdx.x, t = threadIdx.x, i = b*1024 + t;
  int v = (i < n) ? cnt[i] : 0;
  tmp[t] = v; __syncthreads();
  for (int off = 1; off < 1024; off <<= 1){
    int u = (t >= off) ? tmp[t-off] : 0;
    __syncthreads();
    tmp[t] += u;
    __syncthreads();
  }
  if (i < n) pre[i] = tmp[t];
  if (t == 1023) bsum[b] = tmp[t];
}

__global__ void scan_sums_k(int* __restrict__ bsum, int nb){
  if (threadIdx.x == 0){
    int s = 0;
    for (int i = 0; i < nb; i++){ int v = bsum[i]; bsum[i] = s; s += v; }
  }
}

__global__ __launch_bounds__(256)
void scan_finalize_k(const int* __restrict__ pre, const int* __restrict__ bsum,
                     int* __restrict__ offs, int n){
  int i = blockIdx.x*256 + threadIdx.x;
  if (i < n) offs[i+1] = pre[i] + bsum[i >> 10];
  if (i == 0) offs[0] = 0;
}

__global__ __launch_bounds__(256)
void fill_csr_k(const int* __restrict__ dst, const int* __restrict__ src,
                const int* __restrict__ offs, int* __restrict__ cursor,
                int* __restrict__ eids, int* __restrict__ srcs_csr, int e_total){
  int e = blockIdx.x*256 + threadIdx.x;
  if (e < e_total){
    int d = dst[e];
    int p = offs[d] + atomicAdd(&cursor[d], 1);
    eids[p] = e;
    srcs_csr[p] = src[e];
  }
}

// ---------------- small fp32 helpers (weight prep) ----------------

__global__ __launch_bounds__(128)
void vecmat_bias_k(const float* __restrict__ v, const float* __restrict__ B,
                   const float* __restrict__ b2, float* __restrict__ out, int K, int Nc){
  int c = blockIdx.x*128 + threadIdx.x;
  if (c < Nc){
    float s = b2[c];
    for (int k = 0; k < K; k++) s += v[k]*B[(size_t)k*Nc + c];
    out[c] = s;
  }
}

__global__ __launch_bounds__(256)
void sgemm_k(const float* __restrict__ A, const float* __restrict__ B,
             float* __restrict__ C, int M, int K, int Nc){
  __shared__ float As[16][65];
  __shared__ float Bs[16][65];
  int bm = blockIdx.x*64, bn = blockIdx.y*64;
  int tid = threadIdx.x;
  int tx = tid & 15, ty = tid >> 4;
  float acc[4][4] = {};
  for (int k0 = 0; k0 < K; k0 += 16){
    #pragma unroll
    for (int i = 0; i < 4; i++){
      int t = tid + 256*i;
      int r = t >> 4, c = t & 15;
      int gr = bm + r, gc = k0 + c;
      As[c][r] = (gr < M && gc < K) ? A[(size_t)gr*K + gc] : 0.f;
    }
    #pragma unroll
    for (int i = 0; i < 4; i++){
      int t = tid + 256*i;
      int r = t >> 6, c = t & 63;
      int gr = k0 + r, gc = bn + c;
      Bs[r][c] = (gr < K && gc < Nc) ? B[(size_t)gr*Nc + gc] : 0.f;
    }
    __syncthreads();
    #pragma unroll
    for (int kk = 0; kk < 16; kk++){
      float a[4], b[4];
      #pragma unroll
      for (int i = 0; i < 4; i++) a[i] = As[kk][ty*4 + i];
      #pragma unroll
      for (int j = 0; j < 4; j++) b[j] = Bs[kk][tx*4 + j];
      #pragma unroll
      for (int i = 0; i < 4; i++)
        #pragma unroll
        for (int j = 0; j < 4; j++) acc[i][j] += a[i]*b[j];
    }
    __syncthreads();
  }
  #pragma unroll
  for (int i = 0; i < 4; i++){
    int gr = bm + ty*4 + i;
    if (gr >= M) continue;
    #pragma unroll
    for (int j = 0; j < 4; j++){
      int gc = bn + tx*4 + j;
      if (gc < Nc) C[(size_t)gr*Nc + gc] = acc[i][j];
    }
  }
}

// transpose+convert weights: dst[c][k] = src[k][c], bf16, zero-padded to Kpad
__global__ __launch_bounds__(256)
void tconv_k(const float* __restrict__ src, int K, int ldsrc, int Ncols,
             short* __restrict__ dst, int Kpad){
  int c = blockIdx.x;
  int k = blockIdx.y*256 + threadIdx.x;
  if (c < Ncols && k < Kpad)
    dst[(long)c*Kpad + k] = (k < K) ? f2bf(src[(long)k*ldsrc + c]) : (short)0;
}

// B' for post GEMM
__global__ __launch_bounds__(256)
void btpost_k(const float* __restrict__ Wpost, int F, int Kpad,
              short* __restrict__ dst){
  int cp = blockIdx.x;                 // 0..399
  int k = blockIdx.y*256 + threadIdx.x;
  if (k >= Kpad) return;
  int g = cp / 80, c = cp - g*80;
  float v = 0.f;
  if (k < F){ if (g == 0) v = Wpost[(long)k*80 + c]; }
  else if (k < 7*F) v = Wpost[(long)(F + g*6*F + (k - F))*80 + c];
  dst[(long)cp*Kpad + k] = f2bf(v);
}

__global__ __launch_bounds__(256)
void cvt_rows_k(const float* __restrict__ src, int K, short* __restrict__ dst,
                int ldd, long total){
  long i = (long)blockIdx.x*256 + threadIdx.x;
  if (i >= total) return;
  int n = (int)(i / K), c = (int)(i - (long)n*K);
  dst[(long)n*ldd + c] = f2bf(src[i]);
}

// ---------------- persistent-B MFMA GEMM (K <= 128, Bt: [ncols][128] bf16) ------
// A direct global->register fragments, sequential rows. 8 waves/block, 32 rows
// per wave-tile, grid-stride over tiles. blockIdx.y slices columns by NFR*16.
// Epilogue: per-wave LDS stage in 8-row quarters -> v8s full-line coalesced
// stores. Small LDS footprint => 4 blocks/CU (32 waves, HW max).
// wlim: number of storable columns (multiple of 8, <= ldc - bn).
template<int NFR, bool A_F32, bool C_F32, bool RELU>
__global__ __launch_bounds__(512)
void egemm_k(const void* __restrict__ Av, long lda, int Kreal,
             const short* __restrict__ Bt, const float* __restrict__ bias,
             void* __restrict__ Cv, long ldc, int M, int ncols, int wlim)
{
  constexpr int BN = NFR*16;
  constexpr int PITCH = BN + 8;           // stage pitch (shorts)
  constexpr int NCH = 2*NFR;              // v8s chunks per row
  __shared__ short Bs[BN][136];
  __shared__ short stage[8*8*PITCH];      // 8 waves x 8 rows
  const float* Af = (const float*)Av;
  const short* Ab = (const short*)Av;
  short* Cb = (short*)Cv;
  float* Cf = (float*)Cv;

  int bn = blockIdx.y*BN;
  for (int u = threadIdx.x; u < BN*16; u += 512){
    int c = u >> 4, k8 = (u & 15)*8;
    v8s vv = (v8s)0;
    if (bn + c < ncols) vv = *(const v8s*)(Bt + (long)(bn + c)*128 + k8);
    *(v8s*)&Bs[c][k8] = vv;
  }
  __syncthreads();

  int lane = threadIdx.x & 63;
  int lr = lane & 15, lkg = lane >> 4;
  int w = threadIdx.x >> 6;
  short* st = stage + w*8*PITCH;
  int w0 = (blockIdx.x*512 + threadIdx.x) >> 6;
  int nw = gridDim.x * 8;
  int Mtiles = (M + 31) >> 5;

  // hoist bias (per-lane column set is tile-invariant)
  float bvs[NFR];
  #pragma unroll
  for (int n = 0; n < NFR; n++) bvs[n] = bias ? bias[bn + n*16 + lr] : 0.f;

  for (int t = w0; t < Mtiles; t += nw){
    int base = t*32;
    long r0 = base + lr;      if (r0 > M-1) r0 = M-1;
    long r1 = base + 16 + lr; if (r1 > M-1) r1 = M-1;

    v8s a0[4], a1[4];
    if constexpr (A_F32){
      const float* p0 = Af + r0*lda;
      const float* p1 = Af + r1*lda;
      #pragma unroll
      for (int ks = 0; ks < 4; ks++){
        int kb = ks*32 + lkg*8;
        v8s o0 = (v8s)0, o1 = (v8s)0;
        if (kb + 3 < Kreal){
          float4 f0 = *(const float4*)(p0 + kb);
          float4 f1 = *(const float4*)(p1 + kb);
          o0[0]=f2bf(f0.x); o0[1]=f2bf(f0.y); o0[2]=f2bf(f0.z); o0[3]=f2bf(f0.w);
          o1[0]=f2bf(f1.x); o1[1]=f2bf(f1.y); o1[2]=f2bf(f1.z); o1[3]=f2bf(f1.w);
        }
        if (kb + 7 < Kreal){
          float4 f0 = *(const float4*)(p0 + kb + 4);
          float4 f1 = *(const float4*)(p1 + kb + 4);
          o0[4]=f2bf(f0.x); o0[5]=f2bf(f0.y); o0[6]=f2bf(f0.z); o0[7]=f2bf(f0.w);
          o1[4]=f2bf(f1.x); o1[5]=f2bf(f1.y); o1[6]=f2bf(f1.z); o1[7]=f2bf(f1.w);
        }
        a0[ks] = o0; a1[ks] = o1;
      }
    } else {
      const short* p0 = Ab + r0*lda + lkg*8;
      const short* p1 = Ab + r1*lda + lkg*8;
      #pragma unroll
      for (int ks = 0; ks < 4; ks++){
        a0[ks] = *(const v8s*)(p0 + ks*32);
        a1[ks] = *(const v8s*)(p1 + ks*32);
      }
    }

    v4f acc0[NFR], acc1[NFR];
    #pragma unroll
    for (int n = 0; n < NFR; n++){ acc0[n] = (v4f)0.f; acc1[n] = (v4f)0.f; }
    #pragma unroll
    for (int ks = 0; ks < 4; ks++){
      #pragma unroll
      for (int n = 0; n < NFR; n++){
        v8s b = *(const v8s*)&Bs[n*16 + lr][ks*32 + lkg*8];
        acc0[n] = __builtin_amdgcn_mfma_f32_16x16x32_bf16(a0[ks], b, acc0[n], 0, 0, 0);
        acc1[n] = __builtin_amdgcn_mfma_f32_16x16x32_bf16(a1[ks], b, acc1[n], 0, 0, 0);
      }
    }

    if constexpr (C_F32){
      #pragma unroll
      for (int n = 0; n < NFR; n++){
        int col = bn + n*16 + lr;
        if (col >= ncols) continue;
        #pragma unroll
        for (int j = 0; j < 4; j++){
          int row = base + lkg*4 + j;
          float v0 = acc0[n][j] + bvs[n];
          float v1 = acc1[n][j] + bvs[n];
          if (RELU){ v0 = fmaxf(v0, 0.f); v1 = fmaxf(v1, 0.f); }
          if (row < M)      Cf[(long)row*ldc + col] = v0;
          if (row + 16 < M) Cf[(long)(row+16)*ldc + col] = v1;
        }
      }
    } else {
      // 4 quarters of 8 rows: q0=rows 0-7(acc0), q1=8-15(acc0), q2=16-23(acc1), q3=24-31(acc1)
      #pragma unroll
      for (int q = 0; q < 4; q++){
        if ((lkg >> 1) == (q & 1)){
          int srow = (lkg & 1)*4;
          #pragma unroll
          for (int n = 0; n < NFR; n++){
            #pragma unroll
            for (int j = 0; j < 4; j++){
              float v = ((q < 2) ? acc0[n][j] : acc1[n][j]) + bvs[n];
              if (RELU) v = fmaxf(v, 0.f);
              st[(srow + j)*PITCH + n*16 + lr] = f2bf(v);
            }
          }
        }
        int rb = base + q*8;
        #pragma unroll
        for (int i = 0; i < (8*NCH + 63)/64; i++){
          int c = i*64 + lane;
          if (c < 8*NCH){
            int r = c/NCH, off8 = (c - r*NCH)*8;
            int grow = rb + r;
            if (grow < M && off8 < wlim - (bn & 0))  // off8 in slice-local cols
              if (bn + off8 < wlim)
                *(v8s*)(Cb + (long)grow*ldc + bn + off8) = *(const v8s*)&st[r*PITCH + off8];
          }
        }
      }
    }
  }
}

// ---------------- fused post GEMM + scale combine ----------------
__global__ __launch_bounds__(512)
void pgemm_k(const short* __restrict__ Ab, int kpad,
             const short* __restrict__ Bt, const float* __restrict__ scl,
             const float* __restrict__ bias, short* __restrict__ C, int M)
{
  __shared__ short Bs[400][40];
  __shared__ short AsSt[10240];   // union: As[128][40] (5120) | stage 8*16*80
  short (*As)[40] = (short(*)[40])AsSt;

  int tid = threadIdx.x;
  int w = tid >> 6, lane = tid & 63;
  int lr = lane & 15, lkg = lane >> 4;
  int bm = blockIdx.x*128;

  v4f acc[25];
  #pragma unroll
  for (int n = 0; n < 25; n++) acc[n] = (v4f)0.f;

  for (int k0 = 0; k0 < kpad; k0 += 32){
    {
      int u = tid;
      int r = u >> 2, c8 = (u & 3)*8;
      int grow = bm + r;
      v8s out = (v8s)0;
      if (grow < M) out = *(const v8s*)(Ab + (long)grow*kpad + k0 + c8);
      *(v8s*)&As[r][c8] = out;
    }
    for (int u = tid; u < 400*4; u += 512){
      int c = u >> 2, k8 = (u & 3)*8;
      *(v8s*)&Bs[c][k8] = *(const v8s*)(Bt + (long)c*kpad + k0 + k8);
    }
    __syncthreads();
    {
      v8s a = *(const v8s*)&As[w*16 + lr][lkg*8];
      #pragma unroll
      for (int n = 0; n < 25; n++){
        v8s b = *(const v8s*)&Bs[n*16 + lr][lkg*8];
        acc[n] = __builtin_amdgcn_mfma_f32_16x16x32_bf16(a, b, acc[n], 0, 0, 0);
      }
    }
    __syncthreads();
  }

  short* st = AsSt + w*16*80;
  float sc[4][5];
  #pragma unroll
  for (int j = 0; j < 4; j++){
    int row = bm + w*16 + lkg*4 + j;
    int rr = row < M ? row : 0;
    #pragma unroll
    for (int g = 0; g < 5; g++) sc[j][g] = scl[rr*5 + g];
  }
  #pragma unroll
  for (int cc = 0; cc < 5; cc++){
    float bv = bias[cc*16 + lr];
    #pragma unroll
    for (int j = 0; j < 4; j++){
      float v = bv;
      #pragma unroll
      for (int g = 0; g < 5; g++) v += sc[j][g]*acc[5*g + cc][j];
      st[(lkg*4 + j)*80 + cc*16 + lr] = f2bf(v);
    }
  }
  #pragma unroll
  for (int i = 0; i < 3; i++){
    int c = i*64 + lane;
    if (c < 160){
      int r = c/10, off = (c - r*10)*8;
      int grow = bm + w*16 + r;
      if (grow < M)
        *(v8s*)(C + (long)grow*128 + off) = *(const v8s*)&st[r*80 + off];
    }
  }
}

// ---------------- per-node aggregation (one wave per node) ----------------
template<int F>
__global__ __launch_bounds__(256)
void aggregate_k(const short* __restrict__ xixj, int ldx,
                 const short* __restrict__ epc, int epoff,
                 const int* __restrict__ eids,
                 const int* __restrict__ offs, const int* __restrict__ srcs_csr,
                 short* __restrict__ aggout, long ldk,
                 float* __restrict__ scl, float avg_lin, float avg_log, int n){
  int wnode = (blockIdx.x*256 + threadIdx.x) >> 6;
  int lane = threadIdx.x & 63;
  if (wnode >= n) return;
  constexpr int C2 = F - 64;
  int beg = offs[wnode], end = offs[wnode+1];
  float xi0 = b2f(xixj[(long)wnode*ldx + lane]);
  float xi1 = (lane < C2) ? b2f(xixj[(long)wnode*ldx + 64 + lane]) : 0.f;
  float s0 = 0.f, q0 = 0.f, mn0 = INFINITY, mx0 = -INFINITY;
  float s1 = 0.f, q1 = 0.f, mn1 = INFINITY, mx1 = -INFINITY;
  for (int p = beg; p < end; p++){
    int s = srcs_csr[p];
    long e = eids[p];
    float h0 = xi0 + b2f(xixj[(long)s*ldx + F + lane]) + b2f(epc[e*192 + epoff + lane]);
    s0 += h0; q0 += h0*h0; mn0 = fminf(mn0, h0); mx0 = fmaxf(mx0, h0);
    if (lane < C2){
      float h1 = xi1 + b2f(xixj[(long)s*ldx + F + 64 + lane]) + b2f(epc[e*192 + epoff + 64 + lane]);
      s1 += h1; q1 += h1*h1; mn1 = fminf(mn1, h1); mx1 = fmaxf(mx1, h1);
    }
  }
  int cnt = end - beg;
  float deg = (float)(cnt > 1 ? cnt : 1);
  if (cnt == 0){ mn0 = 0.f; mx0 = 0.f; mn1 = 0.f; mx1 = 0.f; }
  float mean0 = s0/deg, var0 = q0/deg - mean0*mean0;
  float std0 = sqrtf(fmaxf(var0, 0.f) + 1e-5f);
  short* a = aggout + (long)wnode*ldk;
  a[lane] = f2bf(s0); a[F+lane] = f2bf(mean0); a[2*F+lane] = f2bf(mn0);
  a[3*F+lane] = f2bf(mx0); a[4*F+lane] = f2bf(var0); a[5*F+lane] = f2bf(std0);
  if (lane < C2){
    float mean1 = s1/deg, var1 = q1/deg - mean1*mean1;
    float std1 = sqrtf(fmaxf(var1, 0.f) + 1e-5f);
    int l2 = 64 + lane;
    a[l2] = f2bf(s1); a[F+l2] = f2bf(mean1); a[2*F+l2] = f2bf(mn1);
    a[3*F+l2] = f2bf(mx1); a[4*F+l2] = f2bf(var1); a[5*F+l2] = f2bf(std1);
  }
  if (lane == 0){
    float logd = logf(deg + 1.f);
    scl[wnode*5+0] = 1.f;
    scl[wnode*5+1] = logd/avg_log;
    scl[wnode*5+2] = avg_log/logd;
    scl[wnode*5+3] = deg/avg_lin;
    scl[wnode*5+4] = avg_lin/deg;
  }
}

// ---------------- host orchestration ----------------

extern "C" void kernel_launch(void* const* d_in, const int* in_sizes, int n_in,
                              void* d_out, int out_size, void* d_ws, size_t ws_size,
                              hipStream_t stream){
  const float* x1   = (const float*)d_in[0];
  const int*   ei1  = (const int*)  d_in[1];
  const float* ea1  = (const float*)d_in[2];
  const float* x2   = (const float*)d_in[3];
  const int*   ei2  = (const int*)  d_in[4];
  const float* ea2  = (const float*)d_in[5];
  const float* We1  = (const float*)d_in[6],  *be1   = (const float*)d_in[7];
  const float* Wpre1= (const float*)d_in[8],  *bpre1 = (const float*)d_in[9];
  const float* Wpost1=(const float*)d_in[10], *bpost1= (const float*)d_in[11];
  const float* Wlin1= (const float*)d_in[12], *blin1 = (const float*)d_in[13];
  const float* We2  = (const float*)d_in[14], *be2   = (const float*)d_in[15];
  const float* Wpre2= (const float*)d_in[16], *bpre2 = (const float*)d_in[17];
  const float* Wpost2=(const float*)d_in[18], *bpost2= (const float*)d_in[19];
  const float* Wlin2= (const float*)d_in[20], *blin2 = (const float*)d_in[21];
  const float* Wfc1 = (const float*)d_in[22], *bfc1  = (const float*)d_in[23];
  const float* Wfc2 = (const float*)d_in[24], *bfc2  = (const float*)d_in[25];

  static const double HIST[19] = {240,328,79,39,23,12,11,7,6,5,7,3,1,0,2,0,0,0,1};
  double tot = 0, lin = 0, lg = 0;
  for (int i = 0; i < 19; i++){ tot += HIST[i]; lin += i*HIST[i]; lg += log((double)i + 1.0)*HIST[i]; }
  float avg_lin = (float)(lin/tot), avg_log = (float)(lg/tot);

  const int KP1 = 704, KP2 = 576;   // post GEMM K paddings

  uintptr_t pw = (uintptr_t)d_ws;
  auto carve = [&](size_t b)->void*{ void* r = (void*)pw; pw += (b + 255) & ~(size_t)255; return r; };
  int*   cnt      = (int*)  carve((size_t)NN*4);
  int*   pre      = (int*)  carve((size_t)NN*4);
  int*   bsum     = (int*)  carve(64*4);
  int*   offs     = (int*)  carve((size_t)(NN+1)*4);
  int*   cursor   = (int*)  carve((size_t)NN*4);
  int*   eids     = (int*)  carve((size_t)EE*4);
  int*   srcs_csr = (int*)  carve((size_t)EE*4);
  float* WecA     = (float*)carve(100*100*4);
  float* WecB     = (float*)carve(100*80*4);
  float* Wlf      = (float*)carve(80*80*4);
  float* becf     = (float*)carve(256*4);
  float* blf      = (float*)carve(128*4);
  short* Btep12   = (short*)carve((size_t)192*128*2);
  short* Btij1    = (short*)carve((size_t)208*128*2);
  short* Btij2    = (short*)carve((size_t)160*128*2);
  short* Btpost1  = (short*)carve((size_t)400*KP1*2);
  short* Btpost2  = (short*)carve((size_t)400*KP2*2);
  short* Btlin1   = (short*)carve((size_t)80*128*2);
  short* Btlf     = (short*)carve((size_t)80*128*2);
  short* Btfc2    = (short*)carve((size_t)80*128*2);
  short* Aprime1  = (short*)carve((size_t)NN*KP1*2);   // [x(100) | agg(600) | pad]
  short* Aprime2  = (short*)carve((size_t)NN*KP2*2);   // [x(80)  | agg(480) | pad]
  short* xixjb    = (short*)carve((size_t)NN*224*2);
  short* epc      = (short*)carve((size_t)EE*192*2);   // [ep1(100) | ep2(80) | pad]
  float* scl      = (float*)carve((size_t)NN*5*4);
  short* tpost    = (short*)carve((size_t)NN*128*2);
  short* tD       = (short*)carve((size_t)NN*128*2);

  dim3 blk(256);
  const int NB = (NN + 1023)/1024;
  const int NTILES = (NN + 31)/32;               // 1563
  const int GB_N  = (NTILES + 7)/8;              // 196 node-GEMM blocks (1 tile/wave)
  const int GB_E  = 341;                         // edge-GEMM blocks (x), y=3 -> 1023 total

  // ---- weight prep ----
  sgemm_k<<<dim3(2,2), blk, 0, stream>>>(We1, Wpre1 + 2*100*100, WecA, 100, 100, 100);
  sgemm_k<<<dim3(2,2), blk, 0, stream>>>(We2, Wpre2 + 2*80*80,  WecB, 100, 80, 80);
  sgemm_k<<<dim3(2,2), blk, 0, stream>>>(Wlin2, Wfc1, Wlf, 80, 80, 80);
  hipMemsetAsync(becf, 0, 256*4, stream);
  vecmat_bias_k<<<dim3(1), dim3(128), 0, stream>>>(be1, Wpre1 + 2*100*100, bpre1, becf, 100, 100);
  vecmat_bias_k<<<dim3(1), dim3(128), 0, stream>>>(be2, Wpre2 + 2*80*80,  bpre2, becf + 100, 80, 80);
  vecmat_bias_k<<<dim3(1), dim3(128), 0, stream>>>(blin2, Wfc1, bfc1, blf, 80, 80);
  tconv_k<<<dim3(100,1), blk, 0, stream>>>(WecA, 100, 100, 100, Btep12, 128);
  tconv_k<<<dim3(80,1),  blk, 0, stream>>>(WecB, 100,  80,  80, Btep12 + 100*128, 128);
  hipMemsetAsync(Btep12 + 180*128, 0, (size_t)12*128*2, stream);
  tconv_k<<<dim3(100,1), blk, 0, stream>>>(Wpre1,           100, 100, 100, Btij1,           128);
  tconv_k<<<dim3(100,1), blk, 0, stream>>>(Wpre1 + 100*100, 100, 100, 100, Btij1 + 100*128, 128);
  hipMemsetAsync(Btij1 + 200*128, 0, (size_t)8*128*2, stream);
  tconv_k<<<dim3(80,1),  blk, 0, stream>>>(Wpre2,           80, 80, 80, Btij2,          128);
  tconv_k<<<dim3(80,1),  blk, 0, stream>>>(Wpre2 + 80*80,   80, 80, 80, Btij2 + 80*128, 128);
  btpost_k<<<dim3(400,(KP1+255)/256), blk, 0, stream>>>(Wpost1, 100, KP1, Btpost1);
  btpost_k<<<dim3(400,(KP2+255)/256), blk, 0, stream>>>(Wpost2,  80, KP2, Btpost2);
  tconv_k<<<dim3(80,1), blk, 0, stream>>>(Wlin1, 80, 80, 80, Btlin1, 128);
  tconv_k<<<dim3(80,1), blk, 0, stream>>>(Wlf,   80, 80, 80, Btlf,   128);
  tconv_k<<<dim3(80,1), blk, 0, stream>>>(Wfc2,  80, 80, 80, Btfc2,  128);
  // zero padded A-side buffers once
  hipMemsetAsync(Aprime1, 0, (size_t)NN*KP1*2, stream);
  hipMemsetAsync(Aprime2, 0, (size_t)NN*KP2*2, stream);
  hipMemsetAsync(tpost,   0, (size_t)NN*128*2, stream);
  hipMemsetAsync(tD,      0, (size_t)NN*128*2, stream);

  for (int b = 0; b < 2; b++){
    const float* x  = b ? x2  : x1;
    const int*   ei = b ? ei2 : ei1;
    const float* ea = b ? ea2 : ea1;
    float* outb = (float*)d_out + (size_t)b*NN*80;
    const int* src = ei;
    const int* dst = ei + EE;

    // CSR
    hipMemsetAsync(cnt, 0, (size_t)NN*4, stream);
    hipMemsetAsync(cursor, 0, (size_t)NN*4, stream);
    count_deg_k<<<dim3((EE+255)/256), blk, 0, stream>>>(dst, cnt, EE);
    scan_block_k<<<dim3(NB), dim3(1024), 0, stream>>>(cnt, pre, bsum, NN);
    scan_sums_k<<<dim3(1), dim3(64), 0, stream>>>(bsum, NB);
    scan_finalize_k<<<dim3((NN+255)/256), blk, 0, stream>>>(pre, bsum, offs, NN);
    fill_csr_k<<<dim3((EE+255)/256), blk, 0, stream>>>(dst, src, offs, cursor, eids, srcs_csr, EE);

    // fused edge projection: epc[:, :180] = ea @ [Wec1|Wec2] + [bec1|bec2]
    // NFR=4, y=3 slices of 64 cols; small LDS -> 4 blocks/CU
    egemm_k<4,true,false,false><<<dim3(GB_E,3), dim3(512), 0, stream>>>(
        ea, 100, 100, Btep12, becf, epc, 192, EE, 180, 192);

    // x -> A'1[:,0:100]
    cvt_rows_k<<<dim3((int)(((long)NN*100 + 255)/256)), blk, 0, stream>>>(x, 100, Aprime1, KP1, (long)NN*100);

    // ---- conv1 (F=100) ----
    egemm_k<5,false,false,false><<<dim3(GB_N,3), dim3(512), 0, stream>>>(
        Aprime1, KP1, 0, Btij1, nullptr, xixjb, 224, NN, 200, 200);
    aggregate_k<100><<<dim3((NN+3)/4), blk, 0, stream>>>(
        xixjb, 224, epc, 0, eids, offs, srcs_csr, Aprime1 + 100, KP1, scl, avg_lin, avg_log, NN);
    pgemm_k<<<dim3((NN+127)/128), dim3(512), 0, stream>>>(
        Aprime1, KP1, Btpost1, scl, bpost1, tpost, NN);
    egemm_k<5,false,false,true><<<dim3(GB_N,1), dim3(512), 0, stream>>>(
        tpost, 128, 0, Btlin1, blin1, Aprime2, KP2, NN, 80, 80);

    // ---- conv2 (F=80) ----
    egemm_k<5,false,false,false><<<dim3(GB_N,2), dim3(512), 0, stream>>>(
        Aprime2, KP2, 0, Btij2, nullptr, xixjb, 160, NN, 160, 160);
    aggregate_k<80><<<dim3((NN+3)/4), blk, 0, stream>>>(
        xixjb, 160, epc, 100, eids, offs, srcs_csr, Aprime2 + 80, KP2, scl, avg_lin, avg_log, NN);
    pgemm_k<<<dim3((NN+127)/128), dim3(512), 0, stream>>>(
        Aprime2, KP2, Btpost2, scl, bpost2, tpost, NN);

    // ---- fused lin2∘fc1 (+relu), then fc2 ----
    egemm_k<5,false,false,true><<<dim3(GB_N,1), dim3(512), 0, stream>>>(
        tpost, 128, 0, Btlf, blf, tD, 128, NN, 80, 80);
    egemm_k<5,false,true,false><<<dim3(GB_N,1), dim3(512), 0, stream>>>(
        tD, 128, 0, Btfc2, bfc2, outb, 80, NN, 80, 80);
  }
}

// Round 10
// 1322.284 us; speedup vs baseline: 1.1324x; 1.1324x over previous
//
#include <hip/hip_runtime.h>
#include <cmath>

static constexpr int NN = 50000;   // nodes
static constexpr int EE = 500000;  // edges

typedef short v8s __attribute__((ext_vector_type(8)));
typedef float v4f __attribute__((ext_vector_type(4)));

__device__ inline short f2bf(float x){
  union{float f; unsigned u;} v{x};
  unsigned r = v.u + 0x7fffu + ((v.u >> 16) & 1u);
  return (short)(r >> 16);
}
__device__ inline float b2f(short s){
  union{unsigned u; float f;} v; v.u = ((unsigned)(unsigned short)s) << 16; return v.f;
}
// packed fp32x2 -> bf16x2 (RNE), single VALU op
__device__ inline unsigned cvtpk(float lo, float hi){
  unsigned r;
  asm("v_cvt_pk_bf16_f32 %0, %1, %2" : "=v"(r) : "v"(lo), "v"(hi));
  return r;
}

// ---------------- graph prep ----------------

__global__ __launch_bounds__(256)
void count_deg_k(const int* __restrict__ dst, int* __restrict__ cnt, int e_total){
  int e = blockIdx.x*256 + threadIdx.x;
  if (e < e_total) atomicAdd(&cnt[dst[e]], 1);
}

__global__ __launch_bounds__(1024)
void scan_block_k(const int* __restrict__ cnt, int* __restrict__ pre,
                  int* __restrict__ bsum, int n){
  __shared__ int tmp[1024];
  int b = blockIdx.x, t = threadIdx.x, i = b*1024 + t;
  int v = (i < n) ? cnt[i] : 0;
  tmp[t] = v; __syncthreads();
  for (int off = 1; off < 1024; off <<= 1){
    int u = (t >= off) ? tmp[t-off] : 0;
    __syncthreads();
    tmp[t] += u;
    __syncthreads();
  }
  if (i < n) pre[i] = tmp[t];
  if (t == 1023) bsum[b] = tmp[t];
}

__global__ void scan_sums_k(int* __restrict__ bsum, int nb){
  if (threadIdx.x == 0){
    int s = 0;
    for (int i = 0; i < nb; i++){ int v = bsum[i]; bsum[i] = s; s += v; }
  }
}

__global__ __launch_bounds__(256)
void scan_finalize_k(const int* __restrict__ pre, const int* __restrict__ bsum,
                     int* __restrict__ offs, int n){
  int i = blockIdx.x*256 + threadIdx.x;
  if (i < n) offs[i+1] = pre[i] + bsum[i >> 10];
  if (i == 0) offs[0] = 0;
}

__global__ __launch_bounds__(256)
void fill_csr_k(const int* __restrict__ dst, const int* __restrict__ src,
                const int* __restrict__ offs, int* __restrict__ cursor,
                int2* __restrict__ edg, int e_total){
  int e = blockIdx.x*256 + threadIdx.x;
  if (e < e_total){
    int d = dst[e];
    int p = offs[d] + atomicAdd(&cursor[d], 1);
    edg[p] = make_int2(e, src[e]);
  }
}

// ---------------- weight prep (consolidated) ----------------

struct VJob { const float* v; const float* B; const float* b2; float* out; int K, Nc; };
struct VJobs { VJob j[3]; };
__global__ __launch_bounds__(128)
void vecmat_multi_k(VJobs js){
  const VJob J = js.j[blockIdx.y];
  int c = threadIdx.x;
  if (c < J.Nc){
    float s = J.b2[c];
    for (int k = 0; k < J.K; k++) s += J.v[k]*J.B[(size_t)k*J.Nc + c];
    J.out[c] = s;
  }
}

__global__ __launch_bounds__(256)
void sgemm_k(const float* __restrict__ A, const float* __restrict__ B,
             float* __restrict__ C, int M, int K, int Nc){
  __shared__ float As[16][65];
  __shared__ float Bs[16][65];
  int bm = blockIdx.x*64, bn = blockIdx.y*64;
  int tid = threadIdx.x;
  int tx = tid & 15, ty = tid >> 4;
  float acc[4][4] = {};
  for (int k0 = 0; k0 < K; k0 += 16){
    #pragma unroll
    for (int i = 0; i < 4; i++){
      int t = tid + 256*i;
      int r = t >> 4, c = t & 15;
      int gr = bm + r, gc = k0 + c;
      As[c][r] = (gr < M && gc < K) ? A[(size_t)gr*K + gc] : 0.f;
    }
    #pragma unroll
    for (int i = 0; i < 4; i++){
      int t = tid + 256*i;
      int r = t >> 6, c = t & 63;
      int gr = k0 + r, gc = bn + c;
      Bs[r][c] = (gr < K && gc < Nc) ? B[(size_t)gr*Nc + gc] : 0.f;
    }
    __syncthreads();
    #pragma unroll
    for (int kk = 0; kk < 16; kk++){
      float a[4], b[4];
      #pragma unroll
      for (int i = 0; i < 4; i++) a[i] = As[kk][ty*4 + i];
      #pragma unroll
      for (int j = 0; j < 4; j++) b[j] = Bs[kk][tx*4 + j];
      #pragma unroll
      for (int i = 0; i < 4; i++)
        #pragma unroll
        for (int j = 0; j < 4; j++) acc[i][j] += a[i]*b[j];
    }
    __syncthreads();
  }
  #pragma unroll
  for (int i = 0; i < 4; i++){
    int gr = bm + ty*4 + i;
    if (gr >= M) continue;
    #pragma unroll
    for (int j = 0; j < 4; j++){
      int gc = bn + tx*4 + j;
      if (gc < Nc) C[(size_t)gr*Nc + gc] = acc[i][j];
    }
  }
}

// transpose+convert weights, Kpad=128: dst[c][k] = src[k][c]
struct TJob { const float* src; short* dst; int K, ldsrc, Ncols; };
struct TJobs { TJob j[9]; };
__global__ __launch_bounds__(128)
void tconv_multi_k(TJobs js){
  const TJob J = js.j[blockIdx.y];
  int c = blockIdx.x;
  int k = threadIdx.x;
  if (c < J.Ncols)
    J.dst[(long)c*128 + k] = (k < J.K) ? f2bf(J.src[(long)k*J.ldsrc + c]) : (short)0;
}

// B' for post GEMM
__global__ __launch_bounds__(256)
void btpost_k(const float* __restrict__ Wpost, int F, int Kpad,
              short* __restrict__ dst){
  int cp = blockIdx.x;                 // 0..399
  int k = blockIdx.y*256 + threadIdx.x;
  if (k >= Kpad) return;
  int g = cp / 80, c = cp - g*80;
  float v = 0.f;
  if (k < F){ if (g == 0) v = Wpost[(long)k*80 + c]; }
  else if (k < 7*F) v = Wpost[(long)(F + g*6*F + (k - F))*80 + c];
  dst[(long)cp*Kpad + k] = f2bf(v);
}

__global__ __launch_bounds__(256)
void cvt_rows_k(const float* __restrict__ src, int K, short* __restrict__ dst,
                int ldd, long total){
  long i = (long)blockIdx.x*256 + threadIdx.x;
  if (i >= total) return;
  int n = (int)(i / K), c = (int)(i - (long)n*K);
  dst[(long)n*ldd + c] = f2bf(src[i]);
}

// zero only the pad columns of the staged bf16 buffers
struct ZJob { short* p; int ld, c0, nc, rows; };
struct ZJobs { ZJob j[4]; };
__global__ __launch_bounds__(256)
void zeropad_k(ZJobs js){
  const ZJob J = js.j[blockIdx.y];
  int i = blockIdx.x*256 + threadIdx.x;
  int r = i / J.nc, c = i - r*J.nc;
  if (r < J.rows) J.p[(long)r*J.ld + J.c0 + c] = 0;
}

// ---------------- persistent-B MFMA GEMM (K <= 128, Bt: [ncols][128] bf16) ------
// 256 threads (4 waves), 32 rows per wave-tile, grid-stride; blockIdx.y slices
// columns by NFR*16. A_F32: two-phase load (16 float4 in flight) + cvt_pk.
// Epilogue: per-wave LDS stage in 8-row quarters -> v8s full-line stores.
template<int NFR, bool A_F32, bool C_F32, bool RELU>
__global__ __launch_bounds__(256)
void egemm_k(const void* __restrict__ Av, long lda, int Kreal,
             const short* __restrict__ Bt, const float* __restrict__ bias,
             void* __restrict__ Cv, long ldc, int M, int ncols, int wlim)
{
  constexpr int BN = NFR*16;
  constexpr int PITCH = BN + 8;           // stage pitch (shorts)
  constexpr int NCH = 2*NFR;              // v8s chunks per row
  __shared__ short Bs[BN][136];
  __shared__ short stage[4*8*PITCH];      // 4 waves x 8 rows
  const float* Af = (const float*)Av;
  const short* Ab = (const short*)Av;
  short* Cb = (short*)Cv;
  float* Cf = (float*)Cv;

  int bn = blockIdx.y*BN;
  for (int u = threadIdx.x; u < BN*16; u += 256){
    int c = u >> 4, k8 = (u & 15)*8;
    v8s vv = (v8s)0;
    if (bn + c < ncols) vv = *(const v8s*)(Bt + (long)(bn + c)*128 + k8);
    *(v8s*)&Bs[c][k8] = vv;
  }
  __syncthreads();

  int lane = threadIdx.x & 63;
  int lr = lane & 15, lkg = lane >> 4;
  int w = threadIdx.x >> 6;
  short* st = stage + w*8*PITCH;
  int w0 = (blockIdx.x*256 + threadIdx.x) >> 6;
  int nw = gridDim.x * 4;
  int Mtiles = (M + 31) >> 5;

  float bvs[NFR];
  #pragma unroll
  for (int n = 0; n < NFR; n++) bvs[n] = bias ? bias[bn + n*16 + lr] : 0.f;

  for (int t = w0; t < Mtiles; t += nw){
    int base = t*32;
    long r0 = base + lr;      if (r0 > M-1) r0 = M-1;
    long r1 = base + 16 + lr; if (r1 > M-1) r1 = M-1;

    v8s a0[4], a1[4];
    if constexpr (A_F32){
      const float* p0 = Af + r0*lda;
      const float* p1 = Af + r1*lda;
      float4 f0[8], f1[8];
      #pragma unroll
      for (int ks = 0; ks < 4; ks++){
        int kb = ks*32 + lkg*8;
        bool ok0 = (kb + 3 < Kreal), ok1 = (kb + 7 < Kreal);
        f0[ks*2+0] = ok0 ? *(const float4*)(p0 + kb)     : make_float4(0.f,0.f,0.f,0.f);
        f0[ks*2+1] = ok1 ? *(const float4*)(p0 + kb + 4) : make_float4(0.f,0.f,0.f,0.f);
        f1[ks*2+0] = ok0 ? *(const float4*)(p1 + kb)     : make_float4(0.f,0.f,0.f,0.f);
        f1[ks*2+1] = ok1 ? *(const float4*)(p1 + kb + 4) : make_float4(0.f,0.f,0.f,0.f);
      }
      #pragma unroll
      for (int ks = 0; ks < 4; ks++){
        union { v8s s; unsigned u[4]; } o0, o1;
        o0.u[0] = cvtpk(f0[ks*2].x, f0[ks*2].y);
        o0.u[1] = cvtpk(f0[ks*2].z, f0[ks*2].w);
        o0.u[2] = cvtpk(f0[ks*2+1].x, f0[ks*2+1].y);
        o0.u[3] = cvtpk(f0[ks*2+1].z, f0[ks*2+1].w);
        o1.u[0] = cvtpk(f1[ks*2].x, f1[ks*2].y);
        o1.u[1] = cvtpk(f1[ks*2].z, f1[ks*2].w);
        o1.u[2] = cvtpk(f1[ks*2+1].x, f1[ks*2+1].y);
        o1.u[3] = cvtpk(f1[ks*2+1].z, f1[ks*2+1].w);
        a0[ks] = o0.s; a1[ks] = o1.s;
      }
    } else {
      const short* p0 = Ab + r0*lda + lkg*8;
      const short* p1 = Ab + r1*lda + lkg*8;
      #pragma unroll
      for (int ks = 0; ks < 4; ks++){
        a0[ks] = *(const v8s*)(p0 + ks*32);
        a1[ks] = *(const v8s*)(p1 + ks*32);
      }
    }

    v4f acc0[NFR], acc1[NFR];
    #pragma unroll
    for (int n = 0; n < NFR; n++){ acc0[n] = (v4f)0.f; acc1[n] = (v4f)0.f; }
    #pragma unroll
    for (int ks = 0; ks < 4; ks++){
      #pragma unroll
      for (int n = 0; n < NFR; n++){
        v8s b = *(const v8s*)&Bs[n*16 + lr][ks*32 + lkg*8];
        acc0[n] = __builtin_amdgcn_mfma_f32_16x16x32_bf16(a0[ks], b, acc0[n], 0, 0, 0);
        acc1[n] = __builtin_amdgcn_mfma_f32_16x16x32_bf16(a1[ks], b, acc1[n], 0, 0, 0);
      }
    }

    if constexpr (C_F32){
      #pragma unroll
      for (int n = 0; n < NFR; n++){
        int col = bn + n*16 + lr;
        if (col >= ncols) continue;
        #pragma unroll
        for (int j = 0; j < 4; j++){
          int row = base + lkg*4 + j;
          float v0 = acc0[n][j] + bvs[n];
          float v1 = acc1[n][j] + bvs[n];
          if (RELU){ v0 = fmaxf(v0, 0.f); v1 = fmaxf(v1, 0.f); }
          if (row < M)      Cf[(long)row*ldc + col] = v0;
          if (row + 16 < M) Cf[(long)(row+16)*ldc + col] = v1;
        }
      }
    } else {
      #pragma unroll
      for (int q = 0; q < 4; q++){
        if ((lkg >> 1) == (q & 1)){
          int srow = (lkg & 1)*4;
          #pragma unroll
          for (int n = 0; n < NFR; n++){
            #pragma unroll
            for (int j = 0; j < 4; j++){
              float v = ((q < 2) ? acc0[n][j] : acc1[n][j]) + bvs[n];
              if (RELU) v = fmaxf(v, 0.f);
              st[(srow + j)*PITCH + n*16 + lr] = f2bf(v);
            }
          }
        }
        int rb = base + q*8;
        #pragma unroll
        for (int i = 0; i < (8*NCH + 63)/64; i++){
          int c = i*64 + lane;
          if (c < 8*NCH){
            int r = c/NCH, off8 = (c - r*NCH)*8;
            int grow = rb + r;
            if (grow < M && bn + off8 < wlim)
              *(v8s*)(Cb + (long)grow*ldc + bn + off8) = *(const v8s*)&st[r*PITCH + off8];
          }
        }
      }
    }
  }
}

// ---------------- fused post GEMM + scale combine ----------------
__global__ __launch_bounds__(512)
void pgemm_k(const short* __restrict__ Ab, int kpad,
             const short* __restrict__ Bt, const float* __restrict__ scl,
             const float* __restrict__ bias, short* __restrict__ C, int M)
{
  __shared__ short Bs[400][40];
  __shared__ short AsSt[10240];   // union: As[128][40] (5120) | stage 8*16*80
  short (*As)[40] = (short(*)[40])AsSt;

  int tid = threadIdx.x;
  int w = tid >> 6, lane = tid & 63;
  int lr = lane & 15, lkg = lane >> 4;
  int bm = blockIdx.x*128;

  v4f acc[25];
  #pragma unroll
  for (int n = 0; n < 25; n++) acc[n] = (v4f)0.f;

  for (int k0 = 0; k0 < kpad; k0 += 32){
    {
      int u = tid;
      int r = u >> 2, c8 = (u & 3)*8;
      int grow = bm + r;
      v8s out = (v8s)0;
      if (grow < M) out = *(const v8s*)(Ab + (long)grow*kpad + k0 + c8);
      *(v8s*)&As[r][c8] = out;
    }
    for (int u = tid; u < 400*4; u += 512){
      int c = u >> 2, k8 = (u & 3)*8;
      *(v8s*)&Bs[c][k8] = *(const v8s*)(Bt + (long)c*kpad + k0 + k8);
    }
    __syncthreads();
    {
      v8s a = *(const v8s*)&As[w*16 + lr][lkg*8];
      #pragma unroll
      for (int n = 0; n < 25; n++){
        v8s b = *(const v8s*)&Bs[n*16 + lr][lkg*8];
        acc[n] = __builtin_amdgcn_mfma_f32_16x16x32_bf16(a, b, acc[n], 0, 0, 0);
      }
    }
    __syncthreads();
  }

  short* st = AsSt + w*16*80;
  float sc[4][5];
  #pragma unroll
  for (int j = 0; j < 4; j++){
    int row = bm + w*16 + lkg*4 + j;
    int rr = row < M ? row : 0;
    #pragma unroll
    for (int g = 0; g < 5; g++) sc[j][g] = scl[rr*5 + g];
  }
  #pragma unroll
  for (int cc = 0; cc < 5; cc++){
    float bv = bias[cc*16 + lr];
    #pragma unroll
    for (int j = 0; j < 4; j++){
      float v = bv;
      #pragma unroll
      for (int g = 0; g < 5; g++) v += sc[j][g]*acc[5*g + cc][j];
      st[(lkg*4 + j)*80 + cc*16 + lr] = f2bf(v);
    }
  }
  #pragma unroll
  for (int i = 0; i < 3; i++){
    int c = i*64 + lane;
    if (c < 160){
      int r = c/10, off = (c - r*10)*8;
      int grow = bm + w*16 + r;
      if (grow < M)
        *(v8s*)(C + (long)grow*128 + off) = *(const v8s*)&st[r*80 + off];
    }
  }
}

// ---------------- per-node aggregation (one wave per node) ----------------
template<int F>
__global__ __launch_bounds__(256)
void aggregate_k(const short* __restrict__ xixj, int ldx,
                 const short* __restrict__ epc, int epoff,
                 const int2* __restrict__ edg,
                 const int* __restrict__ offs,
                 short* __restrict__ aggout, long ldk,
                 float* __restrict__ scl, float avg_lin, float avg_log, int n){
  int wnode = (blockIdx.x*256 + threadIdx.x) >> 6;
  int lane = threadIdx.x & 63;
  if (wnode >= n) return;
  constexpr int C2 = F - 64;
  int beg = offs[wnode], end = offs[wnode+1];
  float xi0 = b2f(xixj[(long)wnode*ldx + lane]);
  float xi1 = (lane < C2) ? b2f(xixj[(long)wnode*ldx + 64 + lane]) : 0.f;
  float s0 = 0.f, q0 = 0.f, mn0 = INFINITY, mx0 = -INFINITY;
  float s1 = 0.f, q1 = 0.f, mn1 = INFINITY, mx1 = -INFINITY;
  for (int p = beg; p < end; p++){
    int2 es = edg[p];
    long e = es.x; int s = es.y;
    float h0 = xi0 + b2f(xixj[(long)s*ldx + F + lane]) + b2f(epc[e*192 + epoff + lane]);
    s0 += h0; q0 += h0*h0; mn0 = fminf(mn0, h0); mx0 = fmaxf(mx0, h0);
    if (lane < C2){
      float h1 = xi1 + b2f(xixj[(long)s*ldx + F + 64 + lane]) + b2f(epc[e*192 + epoff + 64 + lane]);
      s1 += h1; q1 += h1*h1; mn1 = fminf(mn1, h1); mx1 = fmaxf(mx1, h1);
    }
  }
  int cnt = end - beg;
  float deg = (float)(cnt > 1 ? cnt : 1);
  if (cnt == 0){ mn0 = 0.f; mx0 = 0.f; mn1 = 0.f; mx1 = 0.f; }
  float mean0 = s0/deg, var0 = q0/deg - mean0*mean0;
  float std0 = sqrtf(fmaxf(var0, 0.f) + 1e-5f);
  short* a = aggout + (long)wnode*ldk;
  a[lane] = f2bf(s0); a[F+lane] = f2bf(mean0); a[2*F+lane] = f2bf(mn0);
  a[3*F+lane] = f2bf(mx0); a[4*F+lane] = f2bf(var0); a[5*F+lane] = f2bf(std0);
  if (lane < C2){
    float mean1 = s1/deg, var1 = q1/deg - mean1*mean1;
    float std1 = sqrtf(fmaxf(var1, 0.f) + 1e-5f);
    int l2 = 64 + lane;
    a[l2] = f2bf(s1); a[F+l2] = f2bf(mean1); a[2*F+l2] = f2bf(mn1);
    a[3*F+l2] = f2bf(mx1); a[4*F+l2] = f2bf(var1); a[5*F+l2] = f2bf(std1);
  }
  if (lane == 0){
    float logd = logf(deg + 1.f);
    scl[wnode*5+0] = 1.f;
    scl[wnode*5+1] = logd/avg_log;
    scl[wnode*5+2] = avg_log/logd;
    scl[wnode*5+3] = deg/avg_lin;
    scl[wnode*5+4] = avg_lin/deg;
  }
}

// ---------------- host orchestration ----------------

extern "C" void kernel_launch(void* const* d_in, const int* in_sizes, int n_in,
                              void* d_out, int out_size, void* d_ws, size_t ws_size,
                              hipStream_t stream){
  const float* x1   = (const float*)d_in[0];
  const int*   ei1  = (const int*)  d_in[1];
  const float* ea1  = (const float*)d_in[2];
  const float* x2   = (const float*)d_in[3];
  const int*   ei2  = (const int*)  d_in[4];
  const float* ea2  = (const float*)d_in[5];
  const float* We1  = (const float*)d_in[6],  *be1   = (const float*)d_in[7];
  const float* Wpre1= (const float*)d_in[8],  *bpre1 = (const float*)d_in[9];
  const float* Wpost1=(const float*)d_in[10], *bpost1= (const float*)d_in[11];
  const float* Wlin1= (const float*)d_in[12], *blin1 = (const float*)d_in[13];
  const float* We2  = (const float*)d_in[14], *be2   = (const float*)d_in[15];
  const float* Wpre2= (const float*)d_in[16], *bpre2 = (const float*)d_in[17];
  const float* Wpost2=(const float*)d_in[18], *bpost2= (const float*)d_in[19];
  const float* Wlin2= (const float*)d_in[20], *blin2 = (const float*)d_in[21];
  const float* Wfc1 = (const float*)d_in[22], *bfc1  = (const float*)d_in[23];
  const float* Wfc2 = (const float*)d_in[24], *bfc2  = (const float*)d_in[25];

  static const double HIST[19] = {240,328,79,39,23,12,11,7,6,5,7,3,1,0,2,0,0,0,1};
  double tot = 0, lin = 0, lg = 0;
  for (int i = 0; i < 19; i++){ tot += HIST[i]; lin += i*HIST[i]; lg += log((double)i + 1.0)*HIST[i]; }
  float avg_lin = (float)(lin/tot), avg_log = (float)(lg/tot);

  const int KP1 = 704, KP2 = 576;   // post GEMM K paddings

  uintptr_t pw = (uintptr_t)d_ws;
  auto carve = [&](size_t b)->void*{ void* r = (void*)pw; pw += (b + 255) & ~(size_t)255; return r; };
  int*   cnt      = (int*)  carve((size_t)NN*4);
  int*   cursor   = (int*)  carve((size_t)NN*4);
  int*   pre      = (int*)  carve((size_t)NN*4);
  int*   bsum     = (int*)  carve(64*4);
  int*   offs     = (int*)  carve((size_t)(NN+1)*4);
  int2*  edg      = (int2*) carve((size_t)EE*8);
  float* WecA     = (float*)carve(100*100*4);
  float* WecB     = (float*)carve(100*80*4);
  float* Wlf      = (float*)carve(80*80*4);
  float* becf     = (float*)carve(256*4);
  float* blf      = (float*)carve(128*4);
  short* Btep12   = (short*)carve((size_t)192*128*2);
  short* Btij1    = (short*)carve((size_t)208*128*2);
  short* Btij2    = (short*)carve((size_t)160*128*2);
  short* Btpost1  = (short*)carve((size_t)400*KP1*2);
  short* Btpost2  = (short*)carve((size_t)400*KP2*2);
  short* Btlin1   = (short*)carve((size_t)80*128*2);
  short* Btlf     = (short*)carve((size_t)80*128*2);
  short* Btfc2    = (short*)carve((size_t)80*128*2);
  short* Aprime1  = (short*)carve((size_t)NN*KP1*2);   // [x(100) | agg(600) | pad4]
  short* Aprime2  = (short*)carve((size_t)NN*KP2*2);   // [x(80)  | agg(480) | pad16]
  short* xixjb    = (short*)carve((size_t)NN*224*2);
  short* epc      = (short*)carve((size_t)EE*192*2);   // [ep1(100) | ep2(80) | pad]
  float* scl      = (float*)carve((size_t)NN*5*4);
  short* tpost    = (short*)carve((size_t)NN*128*2);
  short* tD       = (short*)carve((size_t)NN*128*2);

  dim3 blk(256);
  const int NB = (NN + 1023)/1024;
  const int GB_N = 391;                      // 391*4 waves = 1564 >= 1563 tiles
  const int GB_E = 1024;                     // edge-GEMM blocks (x), grid-stride

  // ---- weight prep ----
  sgemm_k<<<dim3(2,2), blk, 0, stream>>>(We1, Wpre1 + 2*100*100, WecA, 100, 100, 100);
  sgemm_k<<<dim3(2,2), blk, 0, stream>>>(We2, Wpre2 + 2*80*80,  WecB, 100, 80, 80);
  sgemm_k<<<dim3(2,2), blk, 0, stream>>>(Wlin2, Wfc1, Wlf, 80, 80, 80);
  hipMemsetAsync(becf, 0, 256*4, stream);
  {
    VJobs vj;
    vj.j[0] = {be1,  Wpre1 + 2*100*100, bpre1, becf,       100, 100};
    vj.j[1] = {be2,  Wpre2 + 2*80*80,   bpre2, becf + 100,  80,  80};
    vj.j[2] = {blin2, Wfc1,             bfc1,  blf,         80,  80};
    vecmat_multi_k<<<dim3(1,3), dim3(128), 0, stream>>>(vj);
  }
  {
    TJobs tj;
    tj.j[0] = {WecA,            Btep12,            100, 100, 100};
    tj.j[1] = {WecB,            Btep12 + 100*128,  100,  80,  80};
    tj.j[2] = {Wpre1,           Btij1,             100, 100, 100};
    tj.j[3] = {Wpre1 + 100*100, Btij1 + 100*128,   100, 100, 100};
    tj.j[4] = {Wpre2,           Btij2,              80,  80,  80};
    tj.j[5] = {Wpre2 + 80*80,   Btij2 + 80*128,     80,  80,  80};
    tj.j[6] = {Wlin1,           Btlin1,             80,  80,  80};
    tj.j[7] = {Wlf,             Btlf,               80,  80,  80};
    tj.j[8] = {Wfc2,            Btfc2,              80,  80,  80};
    tconv_multi_k<<<dim3(100,9), dim3(128), 0, stream>>>(tj);
  }
  btpost_k<<<dim3(400,(KP1+255)/256), blk, 0, stream>>>(Wpost1, 100, KP1, Btpost1);
  btpost_k<<<dim3(400,(KP2+255)/256), blk, 0, stream>>>(Wpost2,  80, KP2, Btpost2);
  {
    ZJobs zj;
    zj.j[0] = {Aprime1, KP1, 700,  4, NN};
    zj.j[1] = {Aprime2, KP2, 560, 16, NN};
    zj.j[2] = {tpost,   128,  80, 48, NN};
    zj.j[3] = {tD,      128,  80, 48, NN};
    zeropad_k<<<dim3((NN*48 + 255)/256, 4), blk, 0, stream>>>(zj);
  }

  for (int b = 0; b < 2; b++){
    const float* x  = b ? x2  : x1;
    const int*   ei = b ? ei2 : ei1;
    const float* ea = b ? ea2 : ea1;
    float* outb = (float*)d_out + (size_t)b*NN*80;
    const int* src = ei;
    const int* dst = ei + EE;

    // CSR (cnt & cursor are adjacent carves -> one memset)
    hipMemsetAsync(cnt, 0, (uintptr_t)pre - (uintptr_t)cnt, stream);
    count_deg_k<<<dim3((EE+255)/256), blk, 0, stream>>>(dst, cnt, EE);
    scan_block_k<<<dim3(NB), dim3(1024), 0, stream>>>(cnt, pre, bsum, NN);
    scan_sums_k<<<dim3(1), dim3(64), 0, stream>>>(bsum, NB);
    scan_finalize_k<<<dim3((NN+255)/256), blk, 0, stream>>>(pre, bsum, offs, NN);
    fill_csr_k<<<dim3((EE+255)/256), blk, 0, stream>>>(dst, src, offs, cursor, edg, EE);

    // fused edge projection: epc[:, :180] = ea @ [Wec1|Wec2] + [bec1|bec2]
    egemm_k<6,true,false,false><<<dim3(GB_E,2), blk, 0, stream>>>(
        ea, 100, 100, Btep12, becf, epc, 192, EE, 180, 192);

    // x -> A'1[:,0:100]
    cvt_rows_k<<<dim3((int)(((long)NN*100 + 255)/256)), blk, 0, stream>>>(x, 100, Aprime1, KP1, (long)NN*100);

    // ---- conv1 (F=100) ----
    egemm_k<5,false,false,false><<<dim3(GB_N,3), blk, 0, stream>>>(
        Aprime1, KP1, 0, Btij1, nullptr, xixjb, 224, NN, 200, 200);
    aggregate_k<100><<<dim3((NN+3)/4), blk, 0, stream>>>(
        xixjb, 224, epc, 0, edg, offs, Aprime1 + 100, KP1, scl, avg_lin, avg_log, NN);
    pgemm_k<<<dim3((NN+127)/128), dim3(512), 0, stream>>>(
        Aprime1, KP1, Btpost1, scl, bpost1, tpost, NN);
    egemm_k<5,false,false,true><<<dim3(GB_N,1), blk, 0, stream>>>(
        tpost, 128, 0, Btlin1, blin1, Aprime2, KP2, NN, 80, 80);

    // ---- conv2 (F=80) ----
    egemm_k<5,false,false,false><<<dim3(GB_N,2), blk, 0, stream>>>(
        Aprime2, KP2, 0, Btij2, nullptr, xixjb, 160, NN, 160, 160);
    aggregate_k<80><<<dim3((NN+3)/4), blk, 0, stream>>>(
        xixjb, 160, epc, 100, edg, offs, Aprime2 + 80, KP2, scl, avg_lin, avg_log, NN);
    pgemm_k<<<dim3((NN+127)/128), dim3(512), 0, stream>>>(
        Aprime2, KP2, Btpost2, scl, bpost2, tpost, NN);

    // ---- fused lin2∘fc1 (+relu), then fc2 ----
    egemm_k<5,false,false,true><<<dim3(GB_N,1), blk, 0, stream>>>(
        tpost, 128, 0, Btlf, blf, tD, 128, NN, 80, 80);
    egemm_k<5,false,true,false><<<dim3(GB_N,1), blk, 0, stream>>>(
        tD, 128, 0, Btfc2, bfc2, outb, 80, NN, 80, 80);
  }
}

// Round 11
// 1221.565 us; speedup vs baseline: 1.2258x; 1.0825x over previous
//
#include <hip/hip_runtime.h>
#include <cmath>

static constexpr int NN = 50000;   // nodes
static constexpr int EE = 500000;  // edges

typedef short v8s __attribute__((ext_vector_type(8)));
typedef float v4f __attribute__((ext_vector_type(4)));

__device__ inline short f2bf(float x){
  union{float f; unsigned u;} v{x};
  unsigned r = v.u + 0x7fffu + ((v.u >> 16) & 1u);
  return (short)(r >> 16);
}
__device__ inline float b2f(short s){
  union{unsigned u; float f;} v; v.u = ((unsigned)(unsigned short)s) << 16; return v.f;
}
// packed fp32x2 -> bf16x2 (RNE), single VALU op
__device__ inline unsigned cvtpk(float lo, float hi){
  unsigned r;
  asm("v_cvt_pk_bf16_f32 %0, %1, %2" : "=v"(r) : "v"(lo), "v"(hi));
  return r;
}
// async global->LDS, 16B per lane: LDS dest = base + lane*16 (wave-uniform base)
__device__ inline void gload16(const void* gp, void* lp){
  __builtin_amdgcn_global_load_lds(
      (const __attribute__((address_space(1))) void*)gp,
      (__attribute__((address_space(3))) void*)lp,
      16, 0, 0);
}

// ---------------- graph prep ----------------

__global__ __launch_bounds__(256)
void count_deg_k(const int* __restrict__ dst, int* __restrict__ cnt, int e_total){
  int e = blockIdx.x*256 + threadIdx.x;
  if (e < e_total) atomicAdd(&cnt[dst[e]], 1);
}

__global__ __launch_bounds__(1024)
void scan_block_k(const int* __restrict__ cnt, int* __restrict__ pre,
                  int* __restrict__ bsum, int n){
  __shared__ int tmp[1024];
  int b = blockIdx.x, t = threadIdx.x, i = b*1024 + t;
  int v = (i < n) ? cnt[i] : 0;
  tmp[t] = v; __syncthreads();
  for (int off = 1; off < 1024; off <<= 1){
    int u = (t >= off) ? tmp[t-off] : 0;
    __syncthreads();
    tmp[t] += u;
    __syncthreads();
  }
  if (i < n) pre[i] = tmp[t];
  if (t == 1023) bsum[b] = tmp[t];
}

__global__ void scan_sums_k(int* __restrict__ bsum, int nb){
  if (threadIdx.x == 0){
    int s = 0;
    for (int i = 0; i < nb; i++){ int v = bsum[i]; bsum[i] = s; s += v; }
  }
}

__global__ __launch_bounds__(256)
void scan_finalize_k(const int* __restrict__ pre, const int* __restrict__ bsum,
                     int* __restrict__ offs, int n){
  int i = blockIdx.x*256 + threadIdx.x;
  if (i < n) offs[i+1] = pre[i] + bsum[i >> 10];
  if (i == 0) offs[0] = 0;
}

__global__ __launch_bounds__(256)
void fill_csr_k(const int* __restrict__ dst, const int* __restrict__ src,
                const int* __restrict__ offs, int* __restrict__ cursor,
                int* __restrict__ srcs_csr, int* __restrict__ pos, int e_total){
  int e = blockIdx.x*256 + threadIdx.x;
  if (e < e_total){
    int d = dst[e];
    int p = offs[d] + atomicAdd(&cursor[d], 1);
    srcs_csr[p] = src[e];
    pos[e] = p;
  }
}

// ---------------- weight prep (consolidated) ----------------

struct VJob { const float* v; const float* B; const float* b2; float* out; int K, Nc; };
struct VJobs { VJob j[3]; };
__global__ __launch_bounds__(128)
void vecmat_multi_k(VJobs js){
  const VJob J = js.j[blockIdx.y];
  int c = threadIdx.x;
  if (c < J.Nc){
    float s = J.b2[c];
    for (int k = 0; k < J.K; k++) s += J.v[k]*J.B[(size_t)k*J.Nc + c];
    J.out[c] = s;
  }
}

__global__ __launch_bounds__(256)
void sgemm_k(const float* __restrict__ A, const float* __restrict__ B,
             float* __restrict__ C, int M, int K, int Nc){
  __shared__ float As[16][65];
  __shared__ float Bs[16][65];
  int bm = blockIdx.x*64, bn = blockIdx.y*64;
  int tid = threadIdx.x;
  int tx = tid & 15, ty = tid >> 4;
  float acc[4][4] = {};
  for (int k0 = 0; k0 < K; k0 += 16){
    #pragma unroll
    for (int i = 0; i < 4; i++){
      int t = tid + 256*i;
      int r = t >> 4, c = t & 15;
      int gr = bm + r, gc = k0 + c;
      As[c][r] = (gr < M && gc < K) ? A[(size_t)gr*K + gc] : 0.f;
    }
    #pragma unroll
    for (int i = 0; i < 4; i++){
      int t = tid + 256*i;
      int r = t >> 6, c = t & 63;
      int gr = k0 + r, gc = bn + c;
      Bs[r][c] = (gr < K && gc < Nc) ? B[(size_t)gr*Nc + gc] : 0.f;
    }
    __syncthreads();
    #pragma unroll
    for (int kk = 0; kk < 16; kk++){
      float a[4], b[4];
      #pragma unroll
      for (int i = 0; i < 4; i++) a[i] = As[kk][ty*4 + i];
      #pragma unroll
      for (int j = 0; j < 4; j++) b[j] = Bs[kk][tx*4 + j];
      #pragma unroll
      for (int i = 0; i < 4; i++)
        #pragma unroll
        for (int j = 0; j < 4; j++) acc[i][j] += a[i]*b[j];
    }
    __syncthreads();
  }
  #pragma unroll
  for (int i = 0; i < 4; i++){
    int gr = bm + ty*4 + i;
    if (gr >= M) continue;
    #pragma unroll
    for (int j = 0; j < 4; j++){
      int gc = bn + tx*4 + j;
      if (gc < Nc) C[(size_t)gr*Nc + gc] = acc[i][j];
    }
  }
}

// transpose+convert weights, Kpad=128: dst[c][k] = src[k][c]
struct TJob { const float* src; short* dst; int K, ldsrc, Ncols; };
struct TJobs { TJob j[9]; };
__global__ __launch_bounds__(128)
void tconv_multi_k(TJobs js){
  const TJob J = js.j[blockIdx.y];
  int c = blockIdx.x;
  int k = threadIdx.x;
  if (c < J.Ncols)
    J.dst[(long)c*128 + k] = (k < J.K) ? f2bf(J.src[(long)k*J.ldsrc + c]) : (short)0;
}

// B' for post GEMM
__global__ __launch_bounds__(256)
void btpost_k(const float* __restrict__ Wpost, int F, int Kpad,
              short* __restrict__ dst){
  int cp = blockIdx.x;                 // 0..399
  int k = blockIdx.y*256 + threadIdx.x;
  if (k >= Kpad) return;
  int g = cp / 80, c = cp - g*80;
  float v = 0.f;
  if (k < F){ if (g == 0) v = Wpost[(long)k*80 + c]; }
  else if (k < 7*F) v = Wpost[(long)(F + g*6*F + (k - F))*80 + c];
  dst[(long)cp*Kpad + k] = f2bf(v);
}

__global__ __launch_bounds__(256)
void cvt_rows_k(const float* __restrict__ src, int K, short* __restrict__ dst,
                int ldd, long total){
  long i = (long)blockIdx.x*256 + threadIdx.x;
  if (i >= total) return;
  int n = (int)(i / K), c = (int)(i - (long)n*K);
  dst[(long)n*ldd + c] = f2bf(src[i]);
}

// zero only the pad columns of the staged bf16 buffers
struct ZJob { short* p; int ld, c0, nc, rows; };
struct ZJobs { ZJob j[4]; };
__global__ __launch_bounds__(256)
void zeropad_k(ZJobs js){
  const ZJob J = js.j[blockIdx.y];
  int i = blockIdx.x*256 + threadIdx.x;
  int r = i / J.nc, c = i - r*J.nc;
  if (r < J.rows) J.p[(long)r*J.ld + J.c0 + c] = 0;
}

// ---------------- edge-projection GEMM (global_load_lds A, reg B, CSR write) ----
// epc[pos[e]][0:192] = ea[e] @ Bt^T + bias ; one block = one 32-row tile,
// 4 waves x 48 cols. A tile = contiguous 12.8 KB fp32 -> 13 x gload16 chunks.
__global__ __launch_bounds__(256)
void epgemm_k(const float* __restrict__ ea,       // [EE][100] fp32
              const short* __restrict__ Bt,       // [192][128] bf16
              const float* __restrict__ bias,     // [192] (pad zero)
              const int* __restrict__ pos,        // edge -> csr slot
              short* __restrict__ epc)            // [EE][192] csr-ordered
{
  __shared__ float Atile[3456];        // 13824 B (12800 used; chunk-13 pad)
  __shared__ short stage[32*200];      // 12800 B
  int tid = threadIdx.x, w = tid >> 6, lane = tid & 63;
  int lr = lane & 15, lkg = lane >> 4;

  // hoisted B fragments + bias (wave w owns cols w*48 .. w*48+47)
  v8s bfrag[3][4];
  float bvs[3];
  #pragma unroll
  for (int n = 0; n < 3; n++){
    int col = w*48 + n*16 + lr;
    bvs[n] = bias[col];
    #pragma unroll
    for (int ks = 0; ks < 4; ks++)
      bfrag[n][ks] = *(const v8s*)(Bt + (long)col*128 + ks*32 + lkg*8);
  }

  const char* srcbase = (const char*)ea;
  const char* srcend  = srcbase + (long)EE*400 - 16;
  const int Mtiles = EE/32;            // 15625 exactly

  for (int t = blockIdx.x; t < Mtiles; t += gridDim.x){
    long tb = (long)t*12800;
    // ---- stage A tile (async, no VGPR cost) ----
    for (int c = w; c < 13; c += 4){
      const char* src = srcbase + tb + (long)c*1024 + lane*16;
      if (src > srcend) src = srcend;          // clamp: junk lands in LDS pad only
      gload16(src, (char*)Atile + c*1024);
    }
    __syncthreads();                           // drains vmcnt before barrier

    // ---- fragments + MFMA ----
    const float* rp0 = Atile + lr*100;
    const float* rp1 = Atile + (16 + lr)*100;
    v8s a0[4], a1[4];
    #pragma unroll
    for (int ks = 0; ks < 4; ks++){
      float4 lo0, hi0, lo1, hi1;
      if (ks < 3){
        int kb = ks*32 + lkg*8;
        lo0 = *(const float4*)(rp0 + kb); hi0 = *(const float4*)(rp0 + kb + 4);
        lo1 = *(const float4*)(rp1 + kb); hi1 = *(const float4*)(rp1 + kb + 4);
      } else {
        float4 z = make_float4(0.f,0.f,0.f,0.f);
        lo0 = (lkg == 0) ? *(const float4*)(rp0 + 96) : z;
        lo1 = (lkg == 0) ? *(const float4*)(rp1 + 96) : z;
        hi0 = z; hi1 = z;
      }
      union { v8s s; unsigned u[4]; } o0, o1;
      o0.u[0] = cvtpk(lo0.x, lo0.y); o0.u[1] = cvtpk(lo0.z, lo0.w);
      o0.u[2] = cvtpk(hi0.x, hi0.y); o0.u[3] = cvtpk(hi0.z, hi0.w);
      o1.u[0] = cvtpk(lo1.x, lo1.y); o1.u[1] = cvtpk(lo1.z, lo1.w);
      o1.u[2] = cvtpk(hi1.x, hi1.y); o1.u[3] = cvtpk(hi1.z, hi1.w);
      a0[ks] = o0.s; a1[ks] = o1.s;
    }
    v4f acc0[3], acc1[3];
    #pragma unroll
    for (int n = 0; n < 3; n++){ acc0[n] = (v4f)0.f; acc1[n] = (v4f)0.f; }
    #pragma unroll
    for (int ks = 0; ks < 4; ks++){
      #pragma unroll
      for (int n = 0; n < 3; n++){
        acc0[n] = __builtin_amdgcn_mfma_f32_16x16x32_bf16(a0[ks], bfrag[n][ks], acc0[n], 0, 0, 0);
        acc1[n] = __builtin_amdgcn_mfma_f32_16x16x32_bf16(a1[ks], bfrag[n][ks], acc1[n], 0, 0, 0);
      }
    }

    // ---- stage results (bf16) ----
    #pragma unroll
    for (int n = 0; n < 3; n++){
      int col = w*48 + n*16 + lr;
      #pragma unroll
      for (int j = 0; j < 4; j++){
        stage[(lkg*4 + j)*200 + col]      = f2bf(acc0[n][j] + bvs[n]);
        stage[(16 + lkg*4 + j)*200 + col] = f2bf(acc1[n][j] + bvs[n]);
      }
    }
    __syncthreads();

    // ---- cooperative CSR-ordered store: 32 rows x 24 v8s = full 384-B rows ----
    #pragma unroll
    for (int i = 0; i < 3; i++){
      int u = i*256 + tid;
      int r = u / 24, ch = u - r*24;
      int prow = pos[t*32 + r];
      *(v8s*)(epc + (long)prow*192 + ch*8) = *(const v8s*)&stage[r*200 + ch*8];
    }
    // next iteration's barrier (after gload issue) protects stage reuse
  }
}

// ---------------- persistent-B MFMA GEMM (K <= 128, Bt: [ncols][128] bf16) ------
// bf16 A, sequential rows, 4 waves, LDS-staged epilogue (full-line stores).
template<int NFR, bool C_F32, bool RELU>
__global__ __launch_bounds__(256)
void egemm_k(const short* __restrict__ Ab, long lda,
             const short* __restrict__ Bt, const float* __restrict__ bias,
             void* __restrict__ Cv, long ldc, int M, int ncols, int wlim)
{
  constexpr int BN = NFR*16;
  constexpr int PITCH = BN + 8;
  constexpr int NCH = 2*NFR;
  __shared__ short Bs[BN][136];
  __shared__ short stage[4*8*PITCH];
  short* Cb = (short*)Cv;
  float* Cf = (float*)Cv;

  int bn = blockIdx.y*BN;
  for (int u = threadIdx.x; u < BN*16; u += 256){
    int c = u >> 4, k8 = (u & 15)*8;
    v8s vv = (v8s)0;
    if (bn + c < ncols) vv = *(const v8s*)(Bt + (long)(bn + c)*128 + k8);
    *(v8s*)&Bs[c][k8] = vv;
  }
  __syncthreads();

  int lane = threadIdx.x & 63;
  int lr = lane & 15, lkg = lane >> 4;
  int w = threadIdx.x >> 6;
  short* st = stage + w*8*PITCH;
  int w0 = (blockIdx.x*256 + threadIdx.x) >> 6;
  int nw = gridDim.x * 4;
  int Mtiles = (M + 31) >> 5;

  float bvs[NFR];
  #pragma unroll
  for (int n = 0; n < NFR; n++) bvs[n] = bias ? bias[bn + n*16 + lr] : 0.f;

  for (int t = w0; t < Mtiles; t += nw){
    int base = t*32;
    long r0 = base + lr;      if (r0 > M-1) r0 = M-1;
    long r1 = base + 16 + lr; if (r1 > M-1) r1 = M-1;

    v8s a0[4], a1[4];
    const short* p0 = Ab + r0*lda + lkg*8;
    const short* p1 = Ab + r1*lda + lkg*8;
    #pragma unroll
    for (int ks = 0; ks < 4; ks++){
      a0[ks] = *(const v8s*)(p0 + ks*32);
      a1[ks] = *(const v8s*)(p1 + ks*32);
    }

    v4f acc0[NFR], acc1[NFR];
    #pragma unroll
    for (int n = 0; n < NFR; n++){ acc0[n] = (v4f)0.f; acc1[n] = (v4f)0.f; }
    #pragma unroll
    for (int ks = 0; ks < 4; ks++){
      #pragma unroll
      for (int n = 0; n < NFR; n++){
        v8s b = *(const v8s*)&Bs[n*16 + lr][ks*32 + lkg*8];
        acc0[n] = __builtin_amdgcn_mfma_f32_16x16x32_bf16(a0[ks], b, acc0[n], 0, 0, 0);
        acc1[n] = __builtin_amdgcn_mfma_f32_16x16x32_bf16(a1[ks], b, acc1[n], 0, 0, 0);
      }
    }

    if constexpr (C_F32){
      #pragma unroll
      for (int n = 0; n < NFR; n++){
        int col = bn + n*16 + lr;
        if (col >= ncols) continue;
        #pragma unroll
        for (int j = 0; j < 4; j++){
          int row = base + lkg*4 + j;
          float v0 = acc0[n][j] + bvs[n];
          float v1 = acc1[n][j] + bvs[n];
          if (RELU){ v0 = fmaxf(v0, 0.f); v1 = fmaxf(v1, 0.f); }
          if (row < M)      Cf[(long)row*ldc + col] = v0;
          if (row + 16 < M) Cf[(long)(row+16)*ldc + col] = v1;
        }
      }
    } else {
      #pragma unroll
      for (int q = 0; q < 4; q++){
        if ((lkg >> 1) == (q & 1)){
          int srow = (lkg & 1)*4;
          #pragma unroll
          for (int n = 0; n < NFR; n++){
            #pragma unroll
            for (int j = 0; j < 4; j++){
              float v = ((q < 2) ? acc0[n][j] : acc1[n][j]) + bvs[n];
              if (RELU) v = fmaxf(v, 0.f);
              st[(srow + j)*PITCH + n*16 + lr] = f2bf(v);
            }
          }
        }
        int rb = base + q*8;
        #pragma unroll
        for (int i = 0; i < (8*NCH + 63)/64; i++){
          int c = i*64 + lane;
          if (c < 8*NCH){
            int r = c/NCH, off8 = (c - r*NCH)*8;
            int grow = rb + r;
            if (grow < M && bn + off8 < wlim)
              *(v8s*)(Cb + (long)grow*ldc + bn + off8) = *(const v8s*)&st[r*PITCH + off8];
          }
        }
      }
    }
  }
}

// ---------------- fused post GEMM + scale combine ----------------
__global__ __launch_bounds__(512)
void pgemm_k(const short* __restrict__ Ab, int kpad,
             const short* __restrict__ Bt, const float* __restrict__ scl,
             const float* __restrict__ bias, short* __restrict__ C, int M)
{
  __shared__ short Bs[400][40];
  __shared__ short AsSt[10240];   // union: As[128][40] (5120) | stage 8*16*80
  short (*As)[40] = (short(*)[40])AsSt;

  int tid = threadIdx.x;
  int w = tid >> 6, lane = tid & 63;
  int lr = lane & 15, lkg = lane >> 4;
  int bm = blockIdx.x*128;

  v4f acc[25];
  #pragma unroll
  for (int n = 0; n < 25; n++) acc[n] = (v4f)0.f;

  for (int k0 = 0; k0 < kpad; k0 += 32){
    {
      int u = tid;
      int r = u >> 2, c8 = (u & 3)*8;
      int grow = bm + r;
      v8s out = (v8s)0;
      if (grow < M) out = *(const v8s*)(Ab + (long)grow*kpad + k0 + c8);
      *(v8s*)&As[r][c8] = out;
    }
    for (int u = tid; u < 400*4; u += 512){
      int c = u >> 2, k8 = (u & 3)*8;
      *(v8s*)&Bs[c][k8] = *(const v8s*)(Bt + (long)c*kpad + k0 + k8);
    }
    __syncthreads();
    {
      v8s a = *(const v8s*)&As[w*16 + lr][lkg*8];
      #pragma unroll
      for (int n = 0; n < 25; n++){
        v8s b = *(const v8s*)&Bs[n*16 + lr][lkg*8];
        acc[n] = __builtin_amdgcn_mfma_f32_16x16x32_bf16(a, b, acc[n], 0, 0, 0);
      }
    }
    __syncthreads();
  }

  short* st = AsSt + w*16*80;
  float sc[4][5];
  #pragma unroll
  for (int j = 0; j < 4; j++){
    int row = bm + w*16 + lkg*4 + j;
    int rr = row < M ? row : 0;
    #pragma unroll
    for (int g = 0; g < 5; g++) sc[j][g] = scl[rr*5 + g];
  }
  #pragma unroll
  for (int cc = 0; cc < 5; cc++){
    float bv = bias[cc*16 + lr];
    #pragma unroll
    for (int j = 0; j < 4; j++){
      float v = bv;
      #pragma unroll
      for (int g = 0; g < 5; g++) v += sc[j][g]*acc[5*g + cc][j];
      st[(lkg*4 + j)*80 + cc*16 + lr] = f2bf(v);
    }
  }
  #pragma unroll
  for (int i = 0; i < 3; i++){
    int c = i*64 + lane;
    if (c < 160){
      int r = c/10, off = (c - r*10)*8;
      int grow = bm + w*16 + r;
      if (grow < M)
        *(v8s*)(C + (long)grow*128 + off) = *(const v8s*)&st[r*80 + off];
    }
  }
}

// ---------------- per-node aggregation (one wave per node) ----------------
// ep rows are CSR-ordered: epc[p] read SEQUENTIALLY as p walks the segment.
template<int F>
__global__ __launch_bounds__(256)
void aggregate_k(const short* __restrict__ xixj, int ldx,
                 const short* __restrict__ epc, int epoff,
                 const int* __restrict__ srcs_csr,
                 const int* __restrict__ offs,
                 short* __restrict__ aggout, long ldk,
                 float* __restrict__ scl, float avg_lin, float avg_log, int n){
  int wnode = (blockIdx.x*256 + threadIdx.x) >> 6;
  int lane = threadIdx.x & 63;
  if (wnode >= n) return;
  constexpr int C2 = F - 64;
  int beg = offs[wnode], end = offs[wnode+1];
  float xi0 = b2f(xixj[(long)wnode*ldx + lane]);
  float xi1 = (lane < C2) ? b2f(xixj[(long)wnode*ldx + 64 + lane]) : 0.f;
  float s0 = 0.f, q0 = 0.f, mn0 = INFINITY, mx0 = -INFINITY;
  float s1 = 0.f, q1 = 0.f, mn1 = INFINITY, mx1 = -INFINITY;
  for (int p = beg; p < end; p++){
    int s = srcs_csr[p];
    float h0 = xi0 + b2f(xixj[(long)s*ldx + F + lane]) + b2f(epc[(long)p*192 + epoff + lane]);
    s0 += h0; q0 += h0*h0; mn0 = fminf(mn0, h0); mx0 = fmaxf(mx0, h0);
    if (lane < C2){
      float h1 = xi1 + b2f(xixj[(long)s*ldx + F + 64 + lane]) + b2f(epc[(long)p*192 + epoff + 64 + lane]);
      s1 += h1; q1 += h1*h1; mn1 = fminf(mn1, h1); mx1 = fmaxf(mx1, h1);
    }
  }
  int cnt = end - beg;
  float deg = (float)(cnt > 1 ? cnt : 1);
  if (cnt == 0){ mn0 = 0.f; mx0 = 0.f; mn1 = 0.f; mx1 = 0.f; }
  float mean0 = s0/deg, var0 = q0/deg - mean0*mean0;
  float std0 = sqrtf(fmaxf(var0, 0.f) + 1e-5f);
  short* a = aggout + (long)wnode*ldk;
  a[lane] = f2bf(s0); a[F+lane] = f2bf(mean0); a[2*F+lane] = f2bf(mn0);
  a[3*F+lane] = f2bf(mx0); a[4*F+lane] = f2bf(var0); a[5*F+lane] = f2bf(std0);
  if (lane < C2){
    float mean1 = s1/deg, var1 = q1/deg - mean1*mean1;
    float std1 = sqrtf(fmaxf(var1, 0.f) + 1e-5f);
    int l2 = 64 + lane;
    a[l2] = f2bf(s1); a[F+l2] = f2bf(mean1); a[2*F+l2] = f2bf(mn1);
    a[3*F+l2] = f2bf(mx1); a[4*F+l2] = f2bf(var1); a[5*F+l2] = f2bf(std1);
  }
  if (lane == 0){
    float logd = logf(deg + 1.f);
    scl[wnode*5+0] = 1.f;
    scl[wnode*5+1] = logd/avg_log;
    scl[wnode*5+2] = avg_log/logd;
    scl[wnode*5+3] = deg/avg_lin;
    scl[wnode*5+4] = avg_lin/deg;
  }
}

// ---------------- host orchestration ----------------

extern "C" void kernel_launch(void* const* d_in, const int* in_sizes, int n_in,
                              void* d_out, int out_size, void* d_ws, size_t ws_size,
                              hipStream_t stream){
  const float* x1   = (const float*)d_in[0];
  const int*   ei1  = (const int*)  d_in[1];
  const float* ea1  = (const float*)d_in[2];
  const float* x2   = (const float*)d_in[3];
  const int*   ei2  = (const int*)  d_in[4];
  const float* ea2  = (const float*)d_in[5];
  const float* We1  = (const float*)d_in[6],  *be1   = (const float*)d_in[7];
  const float* Wpre1= (const float*)d_in[8],  *bpre1 = (const float*)d_in[9];
  const float* Wpost1=(const float*)d_in[10], *bpost1= (const float*)d_in[11];
  const float* Wlin1= (const float*)d_in[12], *blin1 = (const float*)d_in[13];
  const float* We2  = (const float*)d_in[14], *be2   = (const float*)d_in[15];
  const float* Wpre2= (const float*)d_in[16], *bpre2 = (const float*)d_in[17];
  const float* Wpost2=(const float*)d_in[18], *bpost2= (const float*)d_in[19];
  const float* Wlin2= (const float*)d_in[20], *blin2 = (const float*)d_in[21];
  const float* Wfc1 = (const float*)d_in[22], *bfc1  = (const float*)d_in[23];
  const float* Wfc2 = (const float*)d_in[24], *bfc2  = (const float*)d_in[25];

  static const double HIST[19] = {240,328,79,39,23,12,11,7,6,5,7,3,1,0,2,0,0,0,1};
  double tot = 0, lin = 0, lg = 0;
  for (int i = 0; i < 19; i++){ tot += HIST[i]; lin += i*HIST[i]; lg += log((double)i + 1.0)*HIST[i]; }
  float avg_lin = (float)(lin/tot), avg_log = (float)(lg/tot);

  const int KP1 = 704, KP2 = 576;   // post GEMM K paddings

  uintptr_t pw = (uintptr_t)d_ws;
  auto carve = [&](size_t b)->void*{ void* r = (void*)pw; pw += (b + 255) & ~(size_t)255; return r; };
  int*   cnt      = (int*)  carve((size_t)NN*4);
  int*   cursor   = (int*)  carve((size_t)NN*4);
  int*   pre      = (int*)  carve((size_t)NN*4);
  int*   bsum     = (int*)  carve(64*4);
  int*   offs     = (int*)  carve((size_t)(NN+1)*4);
  int*   srcs_csr = (int*)  carve((size_t)EE*4);
  int*   pos      = (int*)  carve((size_t)EE*4);
  float* WecA     = (float*)carve(100*100*4);
  float* WecB     = (float*)carve(100*80*4);
  float* Wlf      = (float*)carve(80*80*4);
  float* becf     = (float*)carve(256*4);
  float* blf      = (float*)carve(128*4);
  short* Btep12   = (short*)carve((size_t)192*128*2);
  short* Btij1    = (short*)carve((size_t)208*128*2);
  short* Btij2    = (short*)carve((size_t)160*128*2);
  short* Btpost1  = (short*)carve((size_t)400*KP1*2);
  short* Btpost2  = (short*)carve((size_t)400*KP2*2);
  short* Btlin1   = (short*)carve((size_t)80*128*2);
  short* Btlf     = (short*)carve((size_t)80*128*2);
  short* Btfc2    = (short*)carve((size_t)80*128*2);
  short* Aprime1  = (short*)carve((size_t)NN*KP1*2);   // [x(100) | agg(600) | pad4]
  short* Aprime2  = (short*)carve((size_t)NN*KP2*2);   // [x(80)  | agg(480) | pad16]
  short* xixjb    = (short*)carve((size_t)NN*224*2);
  short* epc      = (short*)carve((size_t)EE*192*2);   // CSR-ordered [ep1(100)|ep2(80)|pad]
  float* scl      = (float*)carve((size_t)NN*5*4);
  short* tpost    = (short*)carve((size_t)NN*128*2);
  short* tD       = (short*)carve((size_t)NN*128*2);

  dim3 blk(256);
  const int NB = (NN + 1023)/1024;
  const int GB_N = 391;                      // 391*4 waves = 1564 >= 1563 tiles

  // ---- weight prep ----
  sgemm_k<<<dim3(2,2), blk, 0, stream>>>(We1, Wpre1 + 2*100*100, WecA, 100, 100, 100);
  sgemm_k<<<dim3(2,2), blk, 0, stream>>>(We2, Wpre2 + 2*80*80,  WecB, 100, 80, 80);
  sgemm_k<<<dim3(2,2), blk, 0, stream>>>(Wlin2, Wfc1, Wlf, 80, 80, 80);
  hipMemsetAsync(becf, 0, 256*4, stream);
  {
    VJobs vj;
    vj.j[0] = {be1,  Wpre1 + 2*100*100, bpre1, becf,       100, 100};
    vj.j[1] = {be2,  Wpre2 + 2*80*80,   bpre2, becf + 100,  80,  80};
    vj.j[2] = {blin2, Wfc1,             bfc1,  blf,         80,  80};
    vecmat_multi_k<<<dim3(1,3), dim3(128), 0, stream>>>(vj);
  }
  {
    TJobs tj;
    tj.j[0] = {WecA,            Btep12,            100, 100, 100};
    tj.j[1] = {WecB,            Btep12 + 100*128,  100,  80,  80};
    tj.j[2] = {Wpre1,           Btij1,             100, 100, 100};
    tj.j[3] = {Wpre1 + 100*100, Btij1 + 100*128,   100, 100, 100};
    tj.j[4] = {Wpre2,           Btij2,              80,  80,  80};
    tj.j[5] = {Wpre2 + 80*80,   Btij2 + 80*128,     80,  80,  80};
    tj.j[6] = {Wlin1,           Btlin1,             80,  80,  80};
    tj.j[7] = {Wlf,             Btlf,               80,  80,  80};
    tj.j[8] = {Wfc2,            Btfc2,              80,  80,  80};
    tconv_multi_k<<<dim3(100,9), dim3(128), 0, stream>>>(tj);
  }
  hipMemsetAsync(Btep12 + 180*128, 0, (size_t)12*128*2, stream);
  hipMemsetAsync(Btij1 + 200*128, 0, (size_t)8*128*2, stream);
  btpost_k<<<dim3(400,(KP1+255)/256), blk, 0, stream>>>(Wpost1, 100, KP1, Btpost1);
  btpost_k<<<dim3(400,(KP2+255)/256), blk, 0, stream>>>(Wpost2,  80, KP2, Btpost2);
  {
    ZJobs zj;
    zj.j[0] = {Aprime1, KP1, 700,  4, NN};
    zj.j[1] = {Aprime2, KP2, 560, 16, NN};
    zj.j[2] = {tpost,   128,  80, 48, NN};
    zj.j[3] = {tD,      128,  80, 48, NN};
    zeropad_k<<<dim3((NN*48 + 255)/256, 4), blk, 0, stream>>>(zj);
  }

  for (int b = 0; b < 2; b++){
    const float* x  = b ? x2  : x1;
    const int*   ei = b ? ei2 : ei1;
    const float* ea = b ? ea2 : ea1;
    float* outb = (float*)d_out + (size_t)b*NN*80;
    const int* src = ei;
    const int* dst = ei + EE;

    // CSR (cnt & cursor adjacent -> one memset)
    hipMemsetAsync(cnt, 0, (uintptr_t)pre - (uintptr_t)cnt, stream);
    count_deg_k<<<dim3((EE+255)/256), blk, 0, stream>>>(dst, cnt, EE);
    scan_block_k<<<dim3(NB), dim3(1024), 0, stream>>>(cnt, pre, bsum, NN);
    scan_sums_k<<<dim3(1), dim3(64), 0, stream>>>(bsum, NB);
    scan_finalize_k<<<dim3((NN+255)/256), blk, 0, stream>>>(pre, bsum, offs, NN);
    fill_csr_k<<<dim3((EE+255)/256), blk, 0, stream>>>(dst, src, offs, cursor, srcs_csr, pos, EE);

    // fused edge projection, CSR-ordered output
    epgemm_k<<<dim3(2048), blk, 0, stream>>>(ea, Btep12, becf, pos, epc);

    // x -> A'1[:,0:100]
    cvt_rows_k<<<dim3((int)(((long)NN*100 + 255)/256)), blk, 0, stream>>>(x, 100, Aprime1, KP1, (long)NN*100);

    // ---- conv1 (F=100) ----
    egemm_k<5,false,false><<<dim3(GB_N,3), blk, 0, stream>>>(
        Aprime1, KP1, Btij1, nullptr, xixjb, 224, NN, 200, 200);
    aggregate_k<100><<<dim3((NN+3)/4), blk, 0, stream>>>(
        xixjb, 224, epc, 0, srcs_csr, offs, Aprime1 + 100, KP1, scl, avg_lin, avg_log, NN);
    pgemm_k<<<dim3((NN+127)/128), dim3(512), 0, stream>>>(
        Aprime1, KP1, Btpost1, scl, bpost1, tpost, NN);
    egemm_k<5,false,true><<<dim3(GB_N,1), blk, 0, stream>>>(
        tpost, 128, Btlin1, blin1, Aprime2, KP2, NN, 80, 80);

    // ---- conv2 (F=80) ----
    egemm_k<5,false,false><<<dim3(GB_N,2), blk, 0, stream>>>(
        Aprime2, KP2, Btij2, nullptr, xixjb, 160, NN, 160, 160);
    aggregate_k<80><<<dim3((NN+3)/4), blk, 0, stream>>>(
        xixjb, 160, epc, 100, srcs_csr, offs, Aprime2 + 80, KP2, scl, avg_lin, avg_log, NN);
    pgemm_k<<<dim3((NN+127)/128), dim3(512), 0, stream>>>(
        Aprime2, KP2, Btpost2, scl, bpost2, tpost, NN);

    // ---- fused lin2∘fc1 (+relu), then fc2 ----
    egemm_k<5,false,true><<<dim3(GB_N,1), blk, 0, stream>>>(
        tpost, 128, Btlf, blf, tD, 128, NN, 80, 80);
    egemm_k<5,true,false><<<dim3(GB_N,1), blk, 0, stream>>>(
        tD, 128, Btfc2, bfc2, outb, 80, NN, 80, 80);
  }
}

// Round 12
// 1218.022 us; speedup vs baseline: 1.2294x; 1.0029x over previous
//
#include <hip/hip_runtime.h>
#include <cmath>

static constexpr int NN = 50000;   // nodes
static constexpr int EE = 500000;  // edges

typedef short v8s __attribute__((ext_vector_type(8)));
typedef float v4f __attribute__((ext_vector_type(4)));

__device__ inline short f2bf(float x){
  union{float f; unsigned u;} v{x};
  unsigned r = v.u + 0x7fffu + ((v.u >> 16) & 1u);
  return (short)(r >> 16);
}
__device__ inline float b2f(short s){
  union{unsigned u; float f;} v; v.u = ((unsigned)(unsigned short)s) << 16; return v.f;
}
// packed fp32x2 -> bf16x2 (RNE), single VALU op
__device__ inline unsigned cvtpk(float lo, float hi){
  unsigned r;
  asm("v_cvt_pk_bf16_f32 %0, %1, %2" : "=v"(r) : "v"(lo), "v"(hi));
  return r;
}
// async global->LDS, 16B per lane: LDS dest = base + lane*16 (wave-uniform base)
__device__ inline void gload16(const void* gp, void* lp){
  __builtin_amdgcn_global_load_lds(
      (const __attribute__((address_space(1))) void*)gp,
      (__attribute__((address_space(3))) void*)lp,
      16, 0, 0);
}

// ---------------- graph prep ----------------

__global__ __launch_bounds__(256)
void count_deg_k(const int* __restrict__ dst, int* __restrict__ cnt, int e_total){
  int e = blockIdx.x*256 + threadIdx.x;
  if (e < e_total) atomicAdd(&cnt[dst[e]], 1);
}

__global__ __launch_bounds__(1024)
void scan_block_k(const int* __restrict__ cnt, int* __restrict__ pre,
                  int* __restrict__ bsum, int n){
  __shared__ int tmp[1024];
  int b = blockIdx.x, t = threadIdx.x, i = b*1024 + t;
  int v = (i < n) ? cnt[i] : 0;
  tmp[t] = v; __syncthreads();
  for (int off = 1; off < 1024; off <<= 1){
    int u = (t >= off) ? tmp[t-off] : 0;
    __syncthreads();
    tmp[t] += u;
    __syncthreads();
  }
  if (i < n) pre[i] = tmp[t];
  if (t == 1023) bsum[b] = tmp[t];
}

__global__ void scan_sums_k(int* __restrict__ bsum, int nb){
  if (threadIdx.x == 0){
    int s = 0;
    for (int i = 0; i < nb; i++){ int v = bsum[i]; bsum[i] = s; s += v; }
  }
}

__global__ __launch_bounds__(256)
void scan_finalize_k(const int* __restrict__ pre, const int* __restrict__ bsum,
                     int* __restrict__ offs, int n){
  int i = blockIdx.x*256 + threadIdx.x;
  if (i < n) offs[i+1] = pre[i] + bsum[i >> 10];
  if (i == 0) offs[0] = 0;
}

__global__ __launch_bounds__(256)
void fill_csr_k(const int* __restrict__ dst, const int* __restrict__ src,
                const int* __restrict__ offs, int* __restrict__ cursor,
                int* __restrict__ srcs_csr, int* __restrict__ pos, int e_total){
  int e = blockIdx.x*256 + threadIdx.x;
  if (e < e_total){
    int d = dst[e];
    int p = offs[d] + atomicAdd(&cursor[d], 1);
    srcs_csr[p] = src[e];
    pos[e] = p;
  }
}

// ---------------- weight prep (consolidated) ----------------

struct VJob { const float* v; const float* B; const float* b2; float* out; int K, Nc; };
struct VJobs { VJob j[3]; };
__global__ __launch_bounds__(128)
void vecmat_multi_k(VJobs js){
  const VJob J = js.j[blockIdx.y];
  int c = threadIdx.x;
  if (c < J.Nc){
    float s = J.b2[c];
    for (int k = 0; k < J.K; k++) s += J.v[k]*J.B[(size_t)k*J.Nc + c];
    J.out[c] = s;
  }
}

__global__ __launch_bounds__(256)
void sgemm_k(const float* __restrict__ A, const float* __restrict__ B,
             float* __restrict__ C, int M, int K, int Nc){
  __shared__ float As[16][65];
  __shared__ float Bs[16][65];
  int bm = blockIdx.x*64, bn = blockIdx.y*64;
  int tid = threadIdx.x;
  int tx = tid & 15, ty = tid >> 4;
  float acc[4][4] = {};
  for (int k0 = 0; k0 < K; k0 += 16){
    #pragma unroll
    for (int i = 0; i < 4; i++){
      int t = tid + 256*i;
      int r = t >> 4, c = t & 15;
      int gr = bm + r, gc = k0 + c;
      As[c][r] = (gr < M && gc < K) ? A[(size_t)gr*K + gc] : 0.f;
    }
    #pragma unroll
    for (int i = 0; i < 4; i++){
      int t = tid + 256*i;
      int r = t >> 6, c = t & 63;
      int gr = k0 + r, gc = bn + c;
      Bs[r][c] = (gr < K && gc < Nc) ? B[(size_t)gr*Nc + gc] : 0.f;
    }
    __syncthreads();
    #pragma unroll
    for (int kk = 0; kk < 16; kk++){
      float a[4], b[4];
      #pragma unroll
      for (int i = 0; i < 4; i++) a[i] = As[kk][ty*4 + i];
      #pragma unroll
      for (int j = 0; j < 4; j++) b[j] = Bs[kk][tx*4 + j];
      #pragma unroll
      for (int i = 0; i < 4; i++)
        #pragma unroll
        for (int j = 0; j < 4; j++) acc[i][j] += a[i]*b[j];
    }
    __syncthreads();
  }
  #pragma unroll
  for (int i = 0; i < 4; i++){
    int gr = bm + ty*4 + i;
    if (gr >= M) continue;
    #pragma unroll
    for (int j = 0; j < 4; j++){
      int gc = bn + tx*4 + j;
      if (gc < Nc) C[(size_t)gr*Nc + gc] = acc[i][j];
    }
  }
}

// transpose+convert weights, Kpad=128: dst[c][k] = src[k][c]
struct TJob { const float* src; short* dst; int K, ldsrc, Ncols; };
struct TJobs { TJob j[9]; };
__global__ __launch_bounds__(128)
void tconv_multi_k(TJobs js){
  const TJob J = js.j[blockIdx.y];
  int c = blockIdx.x;
  int k = threadIdx.x;
  if (c < J.Ncols)
    J.dst[(long)c*128 + k] = (k < J.K) ? f2bf(J.src[(long)k*J.ldsrc + c]) : (short)0;
}

// B' for post GEMM
__global__ __launch_bounds__(256)
void btpost_k(const float* __restrict__ Wpost, int F, int Kpad,
              short* __restrict__ dst){
  int cp = blockIdx.x;                 // 0..399
  int k = blockIdx.y*256 + threadIdx.x;
  if (k >= Kpad) return;
  int g = cp / 80, c = cp - g*80;
  float v = 0.f;
  if (k < F){ if (g == 0) v = Wpost[(long)k*80 + c]; }
  else if (k < 7*F) v = Wpost[(long)(F + g*6*F + (k - F))*80 + c];
  dst[(long)cp*Kpad + k] = f2bf(v);
}

__global__ __launch_bounds__(256)
void cvt_rows_k(const float* __restrict__ src, int K, short* __restrict__ dst,
                int ldd, long total){
  long i = (long)blockIdx.x*256 + threadIdx.x;
  if (i >= total) return;
  int n = (int)(i / K), c = (int)(i - (long)n*K);
  dst[(long)n*ldd + c] = f2bf(src[i]);
}

// zero only the pad columns of the staged bf16 buffers
struct ZJob { short* p; int ld, c0, nc, rows; };
struct ZJobs { ZJob j[4]; };
__global__ __launch_bounds__(256)
void zeropad_k(ZJobs js){
  const ZJob J = js.j[blockIdx.y];
  int i = blockIdx.x*256 + threadIdx.x;
  int r = i / J.nc, c = i - r*J.nc;
  if (r < J.rows) J.p[(long)r*J.ld + J.c0 + c] = 0;
}

// ---------------- edge-projection GEMM (pipelined global_load_lds) ----------
// epc[pos[e]][0:192] = ea[e] @ Bt^T + bias ; one block tile = 32 rows,
// 4 waves x 48 cols. A tile (12.8 KB contiguous fp32) double-buffered:
// prefetch tile t+stride, counted vmcnt (never 0 in steady state), raw
// barriers (no vmcnt(0) drain).
__global__ __launch_bounds__(256)
void epgemm_k(const float* __restrict__ ea,       // [EE][100] fp32
              const short* __restrict__ Bt,       // [192][128] bf16
              const float* __restrict__ bias,     // [192] (pad zero)
              const int* __restrict__ pos,        // edge -> csr slot
              short* __restrict__ epc)            // [EE][192] csr-ordered
{
  __shared__ float Atile[2][3328];     // 2 x 13312 B (12800 used + chunk pad)
  __shared__ short stage[32*200];      // 12800 B
  int tid = threadIdx.x, w = tid >> 6, lane = tid & 63;
  int lr = lane & 15, lkg = lane >> 4;

  // hoisted B fragments + bias (wave w owns cols w*48 .. w*48+47); registers only
  v8s bfrag[3][4];
  float bvs[3];
  #pragma unroll
  for (int n = 0; n < 3; n++){
    int col = w*48 + n*16 + lr;
    bvs[n] = bias[col];
    #pragma unroll
    for (int ks = 0; ks < 4; ks++)
      bfrag[n][ks] = *(const v8s*)(Bt + (long)col*128 + ks*32 + lkg*8);
  }

  const char* srcbase = (const char*)ea;
  const char* srcend  = srcbase + (long)EE*400 - 16;
  const int Mtiles = EE/32;            // 15625 exactly
  const int stride = gridDim.x;

  int t0 = blockIdx.x;
  if (t0 >= Mtiles) return;

  // prologue: stage tile t0 into buf 0
  {
    long tb = (long)t0*12800;
    for (int c = w; c < 13; c += 4){
      const char* src = srcbase + tb + (long)c*1024 + lane*16;
      if (src > srcend) src = srcend;
      gload16(src, (char*)&Atile[0][0] + c*1024);
    }
  }

  int cur = 0;
  for (int t = t0; t < Mtiles; t += stride){
    // ---- (A) prefetch next tile into buf cur^1 ----
    int tn = t + stride;
    if (tn < Mtiles){
      long tb = (long)tn*12800;
      for (int c = w; c < 13; c += 4){
        const char* src = srcbase + tb + (long)c*1024 + lane*16;
        if (src > srcend) src = srcend;
        gload16(src, (char*)&Atile[cur^1][0] + c*1024);
      }
      // (B) keep own prefetch in flight; drain everything older
      if (w == 0) asm volatile("s_waitcnt vmcnt(4)" ::: "memory");
      else        asm volatile("s_waitcnt vmcnt(3)" ::: "memory");
    } else {
      asm volatile("s_waitcnt vmcnt(0)" ::: "memory");
    }
    __builtin_amdgcn_sched_barrier(0);
    __builtin_amdgcn_s_barrier();            // (C) buf[cur] visible to all waves

    // ---- (D) fragments + MFMA from buf[cur] ----
    const float* rp0 = &Atile[cur][0] + lr*100;
    const float* rp1 = &Atile[cur][0] + (16 + lr)*100;
    v8s a0[4], a1[4];
    #pragma unroll
    for (int ks = 0; ks < 4; ks++){
      float4 lo0, hi0, lo1, hi1;
      if (ks < 3){
        int kb = ks*32 + lkg*8;
        lo0 = *(const float4*)(rp0 + kb); hi0 = *(const float4*)(rp0 + kb + 4);
        lo1 = *(const float4*)(rp1 + kb); hi1 = *(const float4*)(rp1 + kb + 4);
      } else {
        float4 z = make_float4(0.f,0.f,0.f,0.f);
        lo0 = (lkg == 0) ? *(const float4*)(rp0 + 96) : z;
        lo1 = (lkg == 0) ? *(const float4*)(rp1 + 96) : z;
        hi0 = z; hi1 = z;
      }
      union { v8s s; unsigned u[4]; } o0, o1;
      o0.u[0] = cvtpk(lo0.x, lo0.y); o0.u[1] = cvtpk(lo0.z, lo0.w);
      o0.u[2] = cvtpk(hi0.x, hi0.y); o0.u[3] = cvtpk(hi0.z, hi0.w);
      o1.u[0] = cvtpk(lo1.x, lo1.y); o1.u[1] = cvtpk(lo1.z, lo1.w);
      o1.u[2] = cvtpk(hi1.x, hi1.y); o1.u[3] = cvtpk(hi1.z, hi1.w);
      a0[ks] = o0.s; a1[ks] = o1.s;
    }
    v4f acc0[3], acc1[3];
    #pragma unroll
    for (int n = 0; n < 3; n++){ acc0[n] = (v4f)0.f; acc1[n] = (v4f)0.f; }
    #pragma unroll
    for (int ks = 0; ks < 4; ks++){
      #pragma unroll
      for (int n = 0; n < 3; n++){
        acc0[n] = __builtin_amdgcn_mfma_f32_16x16x32_bf16(a0[ks], bfrag[n][ks], acc0[n], 0, 0, 0);
        acc1[n] = __builtin_amdgcn_mfma_f32_16x16x32_bf16(a1[ks], bfrag[n][ks], acc1[n], 0, 0, 0);
      }
    }

    // ---- stage results (bf16) ----
    #pragma unroll
    for (int n = 0; n < 3; n++){
      int col = w*48 + n*16 + lr;
      #pragma unroll
      for (int j = 0; j < 4; j++){
        stage[(lkg*4 + j)*200 + col]      = f2bf(acc0[n][j] + bvs[n]);
        stage[(16 + lkg*4 + j)*200 + col] = f2bf(acc1[n][j] + bvs[n]);
      }
    }
    // (E) stage coherent across waves, WITHOUT draining vmcnt (prefetch lives on)
    asm volatile("s_waitcnt lgkmcnt(0)" ::: "memory");
    __builtin_amdgcn_sched_barrier(0);
    __builtin_amdgcn_s_barrier();

    // ---- (F) cooperative CSR-ordered store: 32 rows x 24 v8s = 384-B rows ----
    #pragma unroll
    for (int i = 0; i < 3; i++){
      int u = i*256 + tid;
      int r = u / 24, ch = u - r*24;
      int prow = pos[t*32 + r];
      *(v8s*)(epc + (long)prow*192 + ch*8) = *(const v8s*)&stage[r*200 + ch*8];
    }
    cur ^= 1;
  }
}

// ---------------- persistent-B MFMA GEMM (K <= 128, Bt: [ncols][128] bf16) ------
// bf16 A, sequential rows, 4 waves, LDS-staged epilogue (full-line stores).
template<int NFR, bool C_F32, bool RELU>
__global__ __launch_bounds__(256)
void egemm_k(const short* __restrict__ Ab, long lda,
             const short* __restrict__ Bt, const float* __restrict__ bias,
             void* __restrict__ Cv, long ldc, int M, int ncols, int wlim)
{
  constexpr int BN = NFR*16;
  constexpr int PITCH = BN + 8;
  constexpr int NCH = 2*NFR;
  __shared__ short Bs[BN][136];
  __shared__ short stage[4*8*PITCH];
  short* Cb = (short*)Cv;
  float* Cf = (float*)Cv;

  int bn = blockIdx.y*BN;
  for (int u = threadIdx.x; u < BN*16; u += 256){
    int c = u >> 4, k8 = (u & 15)*8;
    v8s vv = (v8s)0;
    if (bn + c < ncols) vv = *(const v8s*)(Bt + (long)(bn + c)*128 + k8);
    *(v8s*)&Bs[c][k8] = vv;
  }
  __syncthreads();

  int lane = threadIdx.x & 63;
  int lr = lane & 15, lkg = lane >> 4;
  int w = threadIdx.x >> 6;
  short* st = stage + w*8*PITCH;
  int w0 = (blockIdx.x*256 + threadIdx.x) >> 6;
  int nw = gridDim.x * 4;
  int Mtiles = (M + 31) >> 5;

  float bvs[NFR];
  #pragma unroll
  for (int n = 0; n < NFR; n++) bvs[n] = bias ? bias[bn + n*16 + lr] : 0.f;

  for (int t = w0; t < Mtiles; t += nw){
    int base = t*32;
    long r0 = base + lr;      if (r0 > M-1) r0 = M-1;
    long r1 = base + 16 + lr; if (r1 > M-1) r1 = M-1;

    v8s a0[4], a1[4];
    const short* p0 = Ab + r0*lda + lkg*8;
    const short* p1 = Ab + r1*lda + lkg*8;
    #pragma unroll
    for (int ks = 0; ks < 4; ks++){
      a0[ks] = *(const v8s*)(p0 + ks*32);
      a1[ks] = *(const v8s*)(p1 + ks*32);
    }

    v4f acc0[NFR], acc1[NFR];
    #pragma unroll
    for (int n = 0; n < NFR; n++){ acc0[n] = (v4f)0.f; acc1[n] = (v4f)0.f; }
    #pragma unroll
    for (int ks = 0; ks < 4; ks++){
      #pragma unroll
      for (int n = 0; n < NFR; n++){
        v8s b = *(const v8s*)&Bs[n*16 + lr][ks*32 + lkg*8];
        acc0[n] = __builtin_amdgcn_mfma_f32_16x16x32_bf16(a0[ks], b, acc0[n], 0, 0, 0);
        acc1[n] = __builtin_amdgcn_mfma_f32_16x16x32_bf16(a1[ks], b, acc1[n], 0, 0, 0);
      }
    }

    if constexpr (C_F32){
      #pragma unroll
      for (int n = 0; n < NFR; n++){
        int col = bn + n*16 + lr;
        if (col >= ncols) continue;
        #pragma unroll
        for (int j = 0; j < 4; j++){
          int row = base + lkg*4 + j;
          float v0 = acc0[n][j] + bvs[n];
          float v1 = acc1[n][j] + bvs[n];
          if (RELU){ v0 = fmaxf(v0, 0.f); v1 = fmaxf(v1, 0.f); }
          if (row < M)      Cf[(long)row*ldc + col] = v0;
          if (row + 16 < M) Cf[(long)(row+16)*ldc + col] = v1;
        }
      }
    } else {
      #pragma unroll
      for (int q = 0; q < 4; q++){
        if ((lkg >> 1) == (q & 1)){
          int srow = (lkg & 1)*4;
          #pragma unroll
          for (int n = 0; n < NFR; n++){
            #pragma unroll
            for (int j = 0; j < 4; j++){
              float v = ((q < 2) ? acc0[n][j] : acc1[n][j]) + bvs[n];
              if (RELU) v = fmaxf(v, 0.f);
              st[(srow + j)*PITCH + n*16 + lr] = f2bf(v);
            }
          }
        }
        int rb = base + q*8;
        #pragma unroll
        for (int i = 0; i < (8*NCH + 63)/64; i++){
          int c = i*64 + lane;
          if (c < 8*NCH){
            int r = c/NCH, off8 = (c - r*NCH)*8;
            int grow = rb + r;
            if (grow < M && bn + off8 < wlim)
              *(v8s*)(Cb + (long)grow*ldc + bn + off8) = *(const v8s*)&st[r*PITCH + off8];
          }
        }
      }
    }
  }
}

// ---------------- fused post GEMM + scale combine ----------------
__global__ __launch_bounds__(512)
void pgemm_k(const short* __restrict__ Ab, int kpad,
             const short* __restrict__ Bt, const float* __restrict__ scl,
             const float* __restrict__ bias, short* __restrict__ C, int M)
{
  __shared__ short Bs[400][40];
  __shared__ short AsSt[10240];   // union: As[128][40] (5120) | stage 8*16*80
  short (*As)[40] = (short(*)[40])AsSt;

  int tid = threadIdx.x;
  int w = tid >> 6, lane = tid & 63;
  int lr = lane & 15, lkg = lane >> 4;
  int bm = blockIdx.x*128;

  v4f acc[25];
  #pragma unroll
  for (int n = 0; n < 25; n++) acc[n] = (v4f)0.f;

  for (int k0 = 0; k0 < kpad; k0 += 32){
    {
      int u = tid;
      int r = u >> 2, c8 = (u & 3)*8;
      int grow = bm + r;
      v8s out = (v8s)0;
      if (grow < M) out = *(const v8s*)(Ab + (long)grow*kpad + k0 + c8);
      *(v8s*)&As[r][c8] = out;
    }
    for (int u = tid; u < 400*4; u += 512){
      int c = u >> 2, k8 = (u & 3)*8;
      *(v8s*)&Bs[c][k8] = *(const v8s*)(Bt + (long)c*kpad + k0 + k8);
    }
    __syncthreads();
    {
      v8s a = *(const v8s*)&As[w*16 + lr][lkg*8];
      #pragma unroll
      for (int n = 0; n < 25; n++){
        v8s b = *(const v8s*)&Bs[n*16 + lr][lkg*8];
        acc[n] = __builtin_amdgcn_mfma_f32_16x16x32_bf16(a, b, acc[n], 0, 0, 0);
      }
    }
    __syncthreads();
  }

  short* st = AsSt + w*16*80;
  float sc[4][5];
  #pragma unroll
  for (int j = 0; j < 4; j++){
    int row = bm + w*16 + lkg*4 + j;
    int rr = row < M ? row : 0;
    #pragma unroll
    for (int g = 0; g < 5; g++) sc[j][g] = scl[rr*5 + g];
  }
  #pragma unroll
  for (int cc = 0; cc < 5; cc++){
    float bv = bias[cc*16 + lr];
    #pragma unroll
    for (int j = 0; j < 4; j++){
      float v = bv;
      #pragma unroll
      for (int g = 0; g < 5; g++) v += sc[j][g]*acc[5*g + cc][j];
      st[(lkg*4 + j)*80 + cc*16 + lr] = f2bf(v);
    }
  }
  #pragma unroll
  for (int i = 0; i < 3; i++){
    int c = i*64 + lane;
    if (c < 160){
      int r = c/10, off = (c - r*10)*8;
      int grow = bm + w*16 + r;
      if (grow < M)
        *(v8s*)(C + (long)grow*128 + off) = *(const v8s*)&st[r*80 + off];
    }
  }
}

// ---------------- per-node aggregation (one wave per node) ----------------
// ep rows are CSR-ordered: epc[p] read SEQUENTIALLY as p walks the segment.
template<int F>
__global__ __launch_bounds__(256)
void aggregate_k(const short* __restrict__ xixj, int ldx,
                 const short* __restrict__ epc, int epoff,
                 const int* __restrict__ srcs_csr,
                 const int* __restrict__ offs,
                 short* __restrict__ aggout, long ldk,
                 float* __restrict__ scl, float avg_lin, float avg_log, int n){
  int wnode = (blockIdx.x*256 + threadIdx.x) >> 6;
  int lane = threadIdx.x & 63;
  if (wnode >= n) return;
  constexpr int C2 = F - 64;
  int beg = offs[wnode], end = offs[wnode+1];
  float xi0 = b2f(xixj[(long)wnode*ldx + lane]);
  float xi1 = (lane < C2) ? b2f(xixj[(long)wnode*ldx + 64 + lane]) : 0.f;
  float s0 = 0.f, q0 = 0.f, mn0 = INFINITY, mx0 = -INFINITY;
  float s1 = 0.f, q1 = 0.f, mn1 = INFINITY, mx1 = -INFINITY;
  for (int p = beg; p < end; p++){
    int s = srcs_csr[p];
    float h0 = xi0 + b2f(xixj[(long)s*ldx + F + lane]) + b2f(epc[(long)p*192 + epoff + lane]);
    s0 += h0; q0 += h0*h0; mn0 = fminf(mn0, h0); mx0 = fmaxf(mx0, h0);
    if (lane < C2){
      float h1 = xi1 + b2f(xixj[(long)s*ldx + F + 64 + lane]) + b2f(epc[(long)p*192 + epoff + 64 + lane]);
      s1 += h1; q1 += h1*h1; mn1 = fminf(mn1, h1); mx1 = fmaxf(mx1, h1);
    }
  }
  int cnt = end - beg;
  float deg = (float)(cnt > 1 ? cnt : 1);
  if (cnt == 0){ mn0 = 0.f; mx0 = 0.f; mn1 = 0.f; mx1 = 0.f; }
  float mean0 = s0/deg, var0 = q0/deg - mean0*mean0;
  float std0 = sqrtf(fmaxf(var0, 0.f) + 1e-5f);
  short* a = aggout + (long)wnode*ldk;
  a[lane] = f2bf(s0); a[F+lane] = f2bf(mean0); a[2*F+lane] = f2bf(mn0);
  a[3*F+lane] = f2bf(mx0); a[4*F+lane] = f2bf(var0); a[5*F+lane] = f2bf(std0);
  if (lane < C2){
    float mean1 = s1/deg, var1 = q1/deg - mean1*mean1;
    float std1 = sqrtf(fmaxf(var1, 0.f) + 1e-5f);
    int l2 = 64 + lane;
    a[l2] = f2bf(s1); a[F+l2] = f2bf(mean1); a[2*F+l2] = f2bf(mn1);
    a[3*F+l2] = f2bf(mx1); a[4*F+l2] = f2bf(var1); a[5*F+l2] = f2bf(std1);
  }
  if (lane == 0){
    float logd = logf(deg + 1.f);
    scl[wnode*5+0] = 1.f;
    scl[wnode*5+1] = logd/avg_log;
    scl[wnode*5+2] = avg_log/logd;
    scl[wnode*5+3] = deg/avg_lin;
    scl[wnode*5+4] = avg_lin/deg;
  }
}

// ---------------- host orchestration ----------------

extern "C" void kernel_launch(void* const* d_in, const int* in_sizes, int n_in,
                              void* d_out, int out_size, void* d_ws, size_t ws_size,
                              hipStream_t stream){
  const float* x1   = (const float*)d_in[0];
  const int*   ei1  = (const int*)  d_in[1];
  const float* ea1  = (const float*)d_in[2];
  const float* x2   = (const float*)d_in[3];
  const int*   ei2  = (const int*)  d_in[4];
  const float* ea2  = (const float*)d_in[5];
  const float* We1  = (const float*)d_in[6],  *be1   = (const float*)d_in[7];
  const float* Wpre1= (const float*)d_in[8],  *bpre1 = (const float*)d_in[9];
  const float* Wpost1=(const float*)d_in[10], *bpost1= (const float*)d_in[11];
  const float* Wlin1= (const float*)d_in[12], *blin1 = (const float*)d_in[13];
  const float* We2  = (const float*)d_in[14], *be2   = (const float*)d_in[15];
  const float* Wpre2= (const float*)d_in[16], *bpre2 = (const float*)d_in[17];
  const float* Wpost2=(const float*)d_in[18], *bpost2= (const float*)d_in[19];
  const float* Wlin2= (const float*)d_in[20], *blin2 = (const float*)d_in[21];
  const float* Wfc1 = (const float*)d_in[22], *bfc1  = (const float*)d_in[23];
  const float* Wfc2 = (const float*)d_in[24], *bfc2  = (const float*)d_in[25];

  static const double HIST[19] = {240,328,79,39,23,12,11,7,6,5,7,3,1,0,2,0,0,0,1};
  double tot = 0, lin = 0, lg = 0;
  for (int i = 0; i < 19; i++){ tot += HIST[i]; lin += i*HIST[i]; lg += log((double)i + 1.0)*HIST[i]; }
  float avg_lin = (float)(lin/tot), avg_log = (float)(lg/tot);

  const int KP1 = 704, KP2 = 576;   // post GEMM K paddings

  uintptr_t pw = (uintptr_t)d_ws;
  auto carve = [&](size_t b)->void*{ void* r = (void*)pw; pw += (b + 255) & ~(size_t)255; return r; };
  int*   cnt      = (int*)  carve((size_t)NN*4);
  int*   cursor   = (int*)  carve((size_t)NN*4);
  int*   pre      = (int*)  carve((size_t)NN*4);
  int*   bsum     = (int*)  carve(64*4);
  int*   offs     = (int*)  carve((size_t)(NN+1)*4);
  int*   srcs_csr = (int*)  carve((size_t)EE*4);
  int*   pos      = (int*)  carve((size_t)EE*4);
  float* WecA     = (float*)carve(100*100*4);
  float* WecB     = (float*)carve(100*80*4);
  float* Wlf      = (float*)carve(80*80*4);
  float* becf     = (float*)carve(256*4);
  float* blf      = (float*)carve(128*4);
  short* Btep12   = (short*)carve((size_t)192*128*2);
  short* Btij1    = (short*)carve((size_t)208*128*2);
  short* Btij2    = (short*)carve((size_t)160*128*2);
  short* Btpost1  = (short*)carve((size_t)400*KP1*2);
  short* Btpost2  = (short*)carve((size_t)400*KP2*2);
  short* Btlin1   = (short*)carve((size_t)80*128*2);
  short* Btlf     = (short*)carve((size_t)80*128*2);
  short* Btfc2    = (short*)carve((size_t)80*128*2);
  short* Aprime1  = (short*)carve((size_t)NN*KP1*2);   // [x(100) | agg(600) | pad4]
  short* Aprime2  = (short*)carve((size_t)NN*KP2*2);   // [x(80)  | agg(480) | pad16]
  short* xixjb    = (short*)carve((size_t)NN*224*2);
  short* epc      = (short*)carve((size_t)EE*192*2);   // CSR-ordered [ep1(100)|ep2(80)|pad]
  float* scl      = (float*)carve((size_t)NN*5*4);
  short* tpost    = (short*)carve((size_t)NN*128*2);
  short* tD       = (short*)carve((size_t)NN*128*2);

  dim3 blk(256);
  const int NB = (NN + 1023)/1024;
  const int GB_N = 391;                      // 391*4 waves = 1564 >= 1563 tiles

  // ---- weight prep ----
  sgemm_k<<<dim3(2,2), blk, 0, stream>>>(We1, Wpre1 + 2*100*100, WecA, 100, 100, 100);
  sgemm_k<<<dim3(2,2), blk, 0, stream>>>(We2, Wpre2 + 2*80*80,  WecB, 100, 80, 80);
  sgemm_k<<<dim3(2,2), blk, 0, stream>>>(Wlin2, Wfc1, Wlf, 80, 80, 80);
  hipMemsetAsync(becf, 0, 256*4, stream);
  {
    VJobs vj;
    vj.j[0] = {be1,  Wpre1 + 2*100*100, bpre1, becf,       100, 100};
    vj.j[1] = {be2,  Wpre2 + 2*80*80,   bpre2, becf + 100,  80,  80};
    vj.j[2] = {blin2, Wfc1,             bfc1,  blf,         80,  80};
    vecmat_multi_k<<<dim3(1,3), dim3(128), 0, stream>>>(vj);
  }
  {
    TJobs tj;
    tj.j[0] = {WecA,            Btep12,            100, 100, 100};
    tj.j[1] = {WecB,            Btep12 + 100*128,  100,  80,  80};
    tj.j[2] = {Wpre1,           Btij1,             100, 100, 100};
    tj.j[3] = {Wpre1 + 100*100, Btij1 + 100*128,   100, 100, 100};
    tj.j[4] = {Wpre2,           Btij2,              80,  80,  80};
    tj.j[5] = {Wpre2 + 80*80,   Btij2 + 80*128,     80,  80,  80};
    tj.j[6] = {Wlin1,           Btlin1,             80,  80,  80};
    tj.j[7] = {Wlf,             Btlf,               80,  80,  80};
    tj.j[8] = {Wfc2,            Btfc2,              80,  80,  80};
    tconv_multi_k<<<dim3(100,9), dim3(128), 0, stream>>>(tj);
  }
  hipMemsetAsync(Btep12 + 180*128, 0, (size_t)12*128*2, stream);
  hipMemsetAsync(Btij1 + 200*128, 0, (size_t)8*128*2, stream);
  btpost_k<<<dim3(400,(KP1+255)/256), blk, 0, stream>>>(Wpost1, 100, KP1, Btpost1);
  btpost_k<<<dim3(400,(KP2+255)/256), blk, 0, stream>>>(Wpost2,  80, KP2, Btpost2);
  {
    ZJobs zj;
    zj.j[0] = {Aprime1, KP1, 700,  4, NN};
    zj.j[1] = {Aprime2, KP2, 560, 16, NN};
    zj.j[2] = {tpost,   128,  80, 48, NN};
    zj.j[3] = {tD,      128,  80, 48, NN};
    zeropad_k<<<dim3((NN*48 + 255)/256, 4), blk, 0, stream>>>(zj);
  }

  for (int b = 0; b < 2; b++){
    const float* x  = b ? x2  : x1;
    const int*   ei = b ? ei2 : ei1;
    const float* ea = b ? ea2 : ea1;
    float* outb = (float*)d_out + (size_t)b*NN*80;
    const int* src = ei;
    const int* dst = ei + EE;

    // CSR (cnt & cursor adjacent -> one memset)
    hipMemsetAsync(cnt, 0, (uintptr_t)pre - (uintptr_t)cnt, stream);
    count_deg_k<<<dim3((EE+255)/256), blk, 0, stream>>>(dst, cnt, EE);
    scan_block_k<<<dim3(NB), dim3(1024), 0, stream>>>(cnt, pre, bsum, NN);
    scan_sums_k<<<dim3(1), dim3(64), 0, stream>>>(bsum, NB);
    scan_finalize_k<<<dim3((NN+255)/256), blk, 0, stream>>>(pre, bsum, offs, NN);
    fill_csr_k<<<dim3((EE+255)/256), blk, 0, stream>>>(dst, src, offs, cursor, srcs_csr, pos, EE);

    // fused edge projection, CSR-ordered output, software-pipelined
    epgemm_k<<<dim3(2048), blk, 0, stream>>>(ea, Btep12, becf, pos, epc);

    // x -> A'1[:,0:100]
    cvt_rows_k<<<dim3((int)(((long)NN*100 + 255)/256)), blk, 0, stream>>>(x, 100, Aprime1, KP1, (long)NN*100);

    // ---- conv1 (F=100) ----
    egemm_k<5,false,false><<<dim3(GB_N,3), blk, 0, stream>>>(
        Aprime1, KP1, Btij1, nullptr, xixjb, 224, NN, 200, 200);
    aggregate_k<100><<<dim3((NN+3)/4), blk, 0, stream>>>(
        xixjb, 224, epc, 0, srcs_csr, offs, Aprime1 + 100, KP1, scl, avg_lin, avg_log, NN);
    pgemm_k<<<dim3((NN+127)/128), dim3(512), 0, stream>>>(
        Aprime1, KP1, Btpost1, scl, bpost1, tpost, NN);
    egemm_k<5,false,true><<<dim3(GB_N,1), blk, 0, stream>>>(
        tpost, 128, Btlin1, blin1, Aprime2, KP2, NN, 80, 80);

    // ---- conv2 (F=80) ----
    egemm_k<5,false,false><<<dim3(GB_N,2), blk, 0, stream>>>(
        Aprime2, KP2, Btij2, nullptr, xixjb, 160, NN, 160, 160);
    aggregate_k<80><<<dim3((NN+3)/4), blk, 0, stream>>>(
        xixjb, 160, epc, 100, srcs_csr, offs, Aprime2 + 80, KP2, scl, avg_lin, avg_log, NN);
    pgemm_k<<<dim3((NN+127)/128), dim3(512), 0, stream>>>(
        Aprime2, KP2, Btpost2, scl, bpost2, tpost, NN);

    // ---- fused lin2∘fc1 (+relu), then fc2 ----
    egemm_k<5,false,true><<<dim3(GB_N,1), blk, 0, stream>>>(
        tpost, 128, Btlf, blf, tD, 128, NN, 80, 80);
    egemm_k<5,true,false><<<dim3(GB_N,1), blk, 0, stream>>>(
        tD, 128, Btfc2, bfc2, outb, 80, NN, 80, 80);
  }
}